// Round 10
// baseline (327.502 us; speedup 1.0000x reference)
//
#include <hip/hip_runtime.h>
#include <hip/hip_bf16.h>

// ---------------------------------------------------------------------------
// Transformer block, B=8 S=1024 H=768 NH=12 HD=64 I=3072.  fp32 in/out,
// bf16 MFMA internals.
// Round 10: new gemmW engine (128x256 tile, wave-out 64x128 = 4x8 frags) for
// QKV and FC1: 12 ds_read feed 32 MFMA (42.7 FLOP/LDS-B vs 32) and A-staging
// amortized over 2x output (staged B/FLOP 1.5x lower) -- attacks the measured
// LDS/stage-bandwidth bound (MfmaUtil pinned at 13% across 6 schedule nulls).
// proj/FC2 (N=768) revert to the round-8 3-buf counted-vmcnt engine.
// attn (swapped-operand softmax) unchanged from round 8.
// ---------------------------------------------------------------------------

typedef __attribute__((ext_vector_type(8))) short bf16x8;
typedef __attribute__((ext_vector_type(4))) float f32x4;
typedef const __attribute__((address_space(3))) char* lds_cp;

#define MFMA16(a, b, c) __builtin_amdgcn_mfma_f32_16x16x32_bf16((a), (b), (c), 0, 0, 0)

// inline-asm LDS read: invisible to compiler alias analysis (no auto-vmcnt).
#define DSR(dst, addr, off) \
    asm volatile("ds_read_b128 %0, %1 offset:" #off : "=v"(dst) : "v"(addr))
#define WAITV4 asm volatile("s_waitcnt vmcnt(4)" ::: "memory")
#define WAITV0 asm volatile("s_waitcnt vmcnt(0)" ::: "memory")
#define WAITLG asm volatile("s_waitcnt lgkmcnt(0)" ::: "memory")
#define SCHEDB __builtin_amdgcn_sched_barrier(0)
// packed f32x2 -> bf16x2 (RNE), single instruction
#define CVTPK(d, lo, hi) \
    asm("v_cvt_pk_bf16_f32 %0, %1, %2" : "=v"(d) : "v"(lo), "v"(hi))

__device__ inline short f2bf(float x) {
    __hip_bfloat16 h = __float2bfloat16(x);
    return *reinterpret_cast<short*>(&h);
}

__device__ inline void gload_lds16(const void* g, void* lds) {
    __builtin_amdgcn_global_load_lds(
        (const __attribute__((address_space(1))) unsigned int*)g,
        (__attribute__((address_space(3))) unsigned int*)lds,
        16, 0, 0);
}

// ---------------------------------------------------------------------------
// Weight prep: W fp32 [K,N] -> Wt bf16 [N,K]   (tiled transpose + cast)
// ---------------------------------------------------------------------------
__global__ __launch_bounds__(256) void transpose_w(
    const float* __restrict__ W, short* __restrict__ Wt, int K, int N) {
    __shared__ float tile[32][33];
    const int tx = threadIdx.x & 31, ty = threadIdx.x >> 5;  // ty 0..7
    const int n0 = blockIdx.x * 32, k0 = blockIdx.y * 32;
#pragma unroll
    for (int i = 0; i < 4; ++i)
        tile[ty + i * 8][tx] = W[(size_t)(k0 + ty + i * 8) * N + n0 + tx];
    __syncthreads();
#pragma unroll
    for (int i = 0; i < 4; ++i)
        Wt[(size_t)(n0 + ty + i * 8) * K + k0 + tx] = f2bf(tile[tx][ty + i * 8]);
}

// ---------------------------------------------------------------------------
// LayerNorm: fp32 [M,768] -> bf16 [M,768]   (one block per row)
// ---------------------------------------------------------------------------
__global__ __launch_bounds__(256) void ln_k(
    const float* __restrict__ x, const float* __restrict__ g,
    const float* __restrict__ b, short* __restrict__ out) {
    const int row = blockIdx.x;
    const int tid = threadIdx.x;
    const float* xr = x + (size_t)row * 768;
    float v[3];
    float s = 0.f, sq = 0.f;
#pragma unroll
    for (int i = 0; i < 3; ++i) {
        v[i] = xr[tid + i * 256];
        s += v[i];
        sq += v[i] * v[i];
    }
#pragma unroll
    for (int off = 32; off >= 1; off >>= 1) {
        s += __shfl_xor(s, off);
        sq += __shfl_xor(sq, off);
    }
    __shared__ float ss[4], ssq[4];
    const int wid = tid >> 6;
    if ((tid & 63) == 0) { ss[wid] = s; ssq[wid] = sq; }
    __syncthreads();
    s = ss[0] + ss[1] + ss[2] + ss[3];
    sq = ssq[0] + ssq[1] + ssq[2] + ssq[3];
    const float mean = s * (1.0f / 768.0f);
    const float var = sq * (1.0f / 768.0f) - mean * mean;  // biased
    const float rstd = rsqrtf(var + 1e-5f);
    short* outr = out + (size_t)row * 768;
#pragma unroll
    for (int i = 0; i < 3; ++i) {
        const int c = tid + i * 256;
        outr[c] = f2bf((v[i] - mean) * rstd * g[c] + b[c]);
    }
}

enum { MODE_BF16 = 0, MODE_QKV = 1, MODE_F32RES = 2, MODE_GELU = 3 };

// ---------------------------------------------------------------------------
// Epilogue writer (shared by both engines).
// ---------------------------------------------------------------------------
template <int MODE>
__device__ inline void epi_store(
    float v, int row, int col, int N,
    const float* __restrict__ resid, float* __restrict__ outf,
    short* __restrict__ outh, short* __restrict__ Qo,
    short* __restrict__ Ko, short* __restrict__ Vto) {
    if constexpr (MODE == MODE_BF16) {
        outh[(size_t)row * N + col] = f2bf(v);
    } else if constexpr (MODE == MODE_GELU) {
        // 0.5v(1+tanh(u)) == v*sigmoid(2u)
        const float u = 0.7978845608028654f * (v + 0.044715f * v * v * v);
        const float gl = v / (1.0f + __expf(-2.0f * u));
        outh[(size_t)row * N + col] = f2bf(gl);
    } else if constexpr (MODE == MODE_F32RES) {
        outf[(size_t)row * N + col] = v + resid[(size_t)row * N + col];
    } else {  // MODE_QKV: Q pre-scaled by 1/8; K; V transposed
        const int bb = row >> 10, s = row & 1023;
        if (col < 768) {
            const int hh = col >> 6, d = col & 63;
            Qo[(((size_t)(bb * 12 + hh)) * 1024 + s) * 64 + d] = f2bf(v * 0.125f);
        } else if (col < 1536) {
            const int c2 = col - 768;
            const int hh = c2 >> 6, d = c2 & 63;
            Ko[(((size_t)(bb * 12 + hh)) * 1024 + s) * 64 + d] = f2bf(v);
        } else {
            const int c2 = col - 1536;
            const int hh = c2 >> 6, d = c2 & 63;
            Vto[(((size_t)(bb * 12 + hh)) * 64 + d) * 1024 + s] = f2bf(v);
        }
    }
}

// ---------------------------------------------------------------------------
// gemmW: C[M,N] = A @ Wt^T + bias.  128x256 tile, BK=32, 4 waves (2x2),
// wave-out 64x128 (4x8 16x16 frags): 12 ds_read_b128 feed 32 MFMA.
// 2 LDS buffers (48KB), depth-1 prefetch: stage(t+1) issued before the MFMA
// cluster, vmcnt(0) after it (latency covered); ONE barrier per K-tile.
// ---------------------------------------------------------------------------
template <int MODE>
__global__ __launch_bounds__(256) void gemmW(
    const short* __restrict__ A, const short* __restrict__ Wt,
    const float* __restrict__ bias, const float* __restrict__ resid,
    float* __restrict__ outf, short* __restrict__ outh,
    short* __restrict__ Qo, short* __restrict__ Ko, short* __restrict__ Vto,
    int M, int N, int K) {
    __shared__ __attribute__((aligned(128))) short Al[2][4096];  // 128x32 per buf
    __shared__ __attribute__((aligned(128))) short Bl[2][8192];  // 256x32 per buf
    const int tid = threadIdx.x;
    const int lane = tid & 63;
    const int w = tid >> 6;
    const int wm = w >> 1, wn = w & 1;
    const int m0 = blockIdx.x * 128, n0 = blockIdx.y * 256;

    f32x4 acc[4][8] = {};

    // staging: linear LDS dest (uniform base + lane*16B), pre-swizzled source
    const int srow = tid >> 2;                                // 0..63
    const int scol = ((tid & 3) * 8) ^ (((tid >> 2) & 3) << 3);
    short* const AlF = &Al[0][0];
    short* const BlF = &Bl[0][0];
    const short* Ab0 = A + (size_t)(m0 + srow) * K + scol;
    const short* Bb0 = Wt + (size_t)(n0 + srow) * K + scol;
    const size_t K64 = (size_t)K * 64;

    auto stageW = [&](int p, int k0s) {
        gload_lds16(Ab0 + k0s,            AlF + p * 4096 + w * 512);
        gload_lds16(Ab0 + K64 + k0s,      AlF + p * 4096 + 2048 + w * 512);
        gload_lds16(Bb0 + k0s,            BlF + p * 8192 + w * 512);
        gload_lds16(Bb0 + K64 + k0s,      BlF + p * 8192 + 2048 + w * 512);
        gload_lds16(Bb0 + 2 * K64 + k0s,  BlF + p * 8192 + 4096 + w * 512);
        gload_lds16(Bb0 + 3 * K64 + k0s,  BlF + p * 8192 + 6144 + w * 512);
    };

    // fragment read offsets (swizzled), bytes within one buffer
    const int l15 = lane & 15;
    const int lcolswz = ((lane >> 4) * 16) ^ ((lane & 3) << 4);
    const int aoff = wm * 4096 + l15 * 64 + lcolswz;   // wm: 64 rows * 64B
    const int boff = wn * 8192 + l15 * 64 + lcolswz;   // wn: 128 rows * 64B
    const lds_cp AlB = (lds_cp)AlF;
    const lds_cp BlB = (lds_cp)BlF;

    const int NT = K >> 5;

    stageW(0, 0);
    WAITV0;
    SCHEDB;

    for (int t = 0; t < NT; ++t) {
        __builtin_amdgcn_s_barrier();   // tile t landed & prior reads retired
        SCHEDB;
        const int p = t & 1;
        const lds_cp Ap = AlB + p * 8192 + aoff;
        const lds_cp Bp = BlB + p * 16384 + boff;
        bf16x8 a0, a1, a2, a3, b0, b1, b2, b3, b4, b5, b6, b7;
        DSR(a0, Ap, 0);
        DSR(a1, Ap, 1024);
        DSR(a2, Ap, 2048);
        DSR(a3, Ap, 3072);
        DSR(b0, Bp, 0);
        DSR(b1, Bp, 1024);
        DSR(b2, Bp, 2048);
        DSR(b3, Bp, 3072);
        DSR(b4, Bp, 4096);
        DSR(b5, Bp, 5120);
        DSR(b6, Bp, 6144);
        DSR(b7, Bp, 7168);

        if (t + 1 < NT) stageW(p ^ 1, (t + 1) << 5);

        WAITLG;
        SCHEDB;

        __builtin_amdgcn_s_setprio(1);
        {
            bf16x8 av[4] = {a0, a1, a2, a3};
            bf16x8 bv[8] = {b0, b1, b2, b3, b4, b5, b6, b7};
#pragma unroll
            for (int mi = 0; mi < 4; ++mi)
#pragma unroll
                for (int ni = 0; ni < 8; ++ni)
                    acc[mi][ni] = MFMA16(av[mi], bv[ni], acc[mi][ni]);
        }
        __builtin_amdgcn_s_setprio(0);
        WAITV0;   // stage(t+1) landed (latency covered by 32 MFMA + reads)
        SCHEDB;
    }

    // Epilogue.  C/D frag layout: col = lane&15, row = (lane>>4)*4 + r.
#pragma unroll
    for (int mi = 0; mi < 4; ++mi)
#pragma unroll
        for (int ni = 0; ni < 8; ++ni)
#pragma unroll
            for (int r = 0; r < 4; ++r) {
                const int row = m0 + wm * 64 + mi * 16 + (lane >> 4) * 4 + r;
                const int col = n0 + wn * 128 + ni * 16 + l15;
                epi_store<MODE>(acc[mi][ni][r] + bias[col], row, col, N,
                                resid, outf, outh, Qo, Ko, Vto);
            }
}

// ---------------------------------------------------------------------------
// gemm3p (round-8 engine): 128x128 tile, BK=32, 3 LDS buffers, counted
// vmcnt(4), 2 barriers per K-tile.  Used for proj and FC2 (N=768).
// ---------------------------------------------------------------------------
template <int MODE>
__global__ __launch_bounds__(256) void gemm3p(
    const short* __restrict__ A, const short* __restrict__ Wt,
    const float* __restrict__ bias, const float* __restrict__ resid,
    float* __restrict__ outf, short* __restrict__ outh,
    short* __restrict__ Qo, short* __restrict__ Ko, short* __restrict__ Vto,
    int M, int N, int K) {
    __shared__ __attribute__((aligned(128))) short Al[3][4096];
    __shared__ __attribute__((aligned(128))) short Bl[3][4096];
    const int tid = threadIdx.x;
    const int lane = tid & 63;
    const int w = tid >> 6;
    const int wm = w >> 1, wn = w & 1;
    const int m0 = blockIdx.x * 128, n0 = blockIdx.y * 128;

    f32x4 acc[4][4] = {};

    const int srow = tid >> 2;
    const int scol = ((tid & 3) * 8) ^ (((tid >> 2) & 3) << 3);
    const short* Abase = A + (size_t)(m0 + srow) * K + scol;
    const short* Bbase = Wt + (size_t)(n0 + srow) * K + scol;
    const size_t K64 = (size_t)K * 64;
    short* const AlF = &Al[0][0];
    short* const BlF = &Bl[0][0];

    auto stageT = [&](int boS, int k0s) {
        gload_lds16(Abase + k0s,       AlF + boS + w * 512);
        gload_lds16(Abase + K64 + k0s, AlF + boS + 2048 + w * 512);
        gload_lds16(Bbase + k0s,       BlF + boS + w * 512);
        gload_lds16(Bbase + K64 + k0s, BlF + boS + 2048 + w * 512);
    };

    const int lrow = lane & 15;
    const int lcolswz = ((lane >> 4) * 16) ^ ((lane & 3) << 4);
    const int aoff = wm * 4096 + lrow * 64 + lcolswz;
    const int boff = wn * 4096 + lrow * 64 + lcolswz;
    const lds_cp AlB = (lds_cp)AlF;
    const lds_cp BlB = (lds_cp)BlF;

    const int NT = K >> 5;

    stageT(0, 0);
    stageT(4096, 32);
    WAITV4;
    SCHEDB;
    __builtin_amdgcn_s_barrier();

    int bo = 0, bo1 = 8192, bo2 = 16384;
    for (int t = 0; t < NT; ++t) {
        const lds_cp Ab = AlB + (bo + aoff);
        const lds_cp Bb = BlB + (bo + boff);
        bf16x8 av0, av1, av2, av3, bv0, bv1, bv2, bv3;
        DSR(av0, Ab, 0);
        DSR(av1, Ab, 1024);
        DSR(av2, Ab, 2048);
        DSR(av3, Ab, 3072);
        DSR(bv0, Bb, 0);
        DSR(bv1, Bb, 1024);
        DSR(bv2, Bb, 2048);
        DSR(bv3, Bb, 3072);

        int ts = t + 2;
        if (ts > NT - 1) ts = NT - 1;
        stageT(bo2 >> 1, ts << 5);
        WAITV4;
        SCHEDB;
        __builtin_amdgcn_s_barrier();
        WAITLG;
        SCHEDB;

        __builtin_amdgcn_s_setprio(1);
        {
            bf16x8 av[4] = {av0, av1, av2, av3};
            bf16x8 bv[4] = {bv0, bv1, bv2, bv3};
#pragma unroll
            for (int mi = 0; mi < 4; ++mi)
#pragma unroll
                for (int ni = 0; ni < 4; ++ni)
                    acc[mi][ni] = MFMA16(av[mi], bv[ni], acc[mi][ni]);
        }
        __builtin_amdgcn_s_setprio(0);
        __builtin_amdgcn_s_barrier();

        const int tmp = bo; bo = bo1; bo1 = bo2; bo2 = tmp;
    }
    WAITV0;

#pragma unroll
    for (int mi = 0; mi < 4; ++mi)
#pragma unroll
        for (int ni = 0; ni < 4; ++ni)
#pragma unroll
            for (int r = 0; r < 4; ++r) {
                const int row = m0 + wm * 64 + mi * 16 + (lane >> 4) * 4 + r;
                const int col = n0 + wn * 64 + ni * 16 + (lane & 15);
                epi_store<MODE>(acc[mi][ni][r] + bias[col], row, col, N,
                                resid, outf, outh, Qo, Ko, Vto);
            }
}

// ---------------------------------------------------------------------------
// Flash attention, swapped-operand softmax (unchanged from round 8).
// ---------------------------------------------------------------------------
__global__ __launch_bounds__(256) void attn_k(
    const short* __restrict__ Q, const short* __restrict__ Kg,
    const short* __restrict__ Vtg, short* __restrict__ out) {
    __shared__ __attribute__((aligned(128))) short Kl[2][64 * 64];
    __shared__ __attribute__((aligned(128))) short Vl[2][64 * 64];
    __shared__ __attribute__((aligned(128))) short Pl[4][16 * 64];
    const int tid = threadIdx.x, lane = tid & 63, w = tid >> 6;
    const int swz = (blockIdx.x & 7) * 192 + (blockIdx.x >> 3);
    const int qt = swz & 15, bh = swz >> 4;
    const int b = bh / 12, h = bh % 12;
    const int q0 = qt * 64 + w * 16;
    const int l15 = lane & 15, g = lane >> 4;

    bf16x8 aq[2];
    const short* Qb = Q + ((size_t)bh * 1024 + q0) * 64;
#pragma unroll
    for (int kk = 0; kk < 2; ++kk)
        aq[kk] = *(const bf16x8*)&Qb[(size_t)l15 * 64 + kk * 32 + g * 8];

    float m_run = -1e30f, l_run = 0.f;
    f32x4 o[4] = {};

    const short* Kb = Kg + (size_t)bh * 1024 * 64;
    const short* Vb = Vtg + (size_t)bh * 64 * 1024;

    const int srr = tid >> 3;
    const int spp = (tid & 7) * 8;
    const int ssc = spp ^ ((srr & 7) << 3);
    auto stage = [&](int buf, int kv0) {
        gload_lds16(Kb + (size_t)(kv0 + srr) * 64 + ssc,        &Kl[buf][w * 512]);
        gload_lds16(Kb + (size_t)(kv0 + 32 + srr) * 64 + ssc,   &Kl[buf][2048 + w * 512]);
        gload_lds16(Vb + (size_t)srr * 1024 + kv0 + ssc,        &Vl[buf][w * 512]);
        gload_lds16(Vb + (size_t)(srr + 32) * 1024 + kv0 + ssc, &Vl[buf][2048 + w * 512]);
    };

    stage(0, 0);
    __syncthreads();

    int buf = 0;
    for (int t = 0; t < 16; ++t) {
        const lds_cp KB = (lds_cp)&Kl[buf][0];
        const lds_cp VB = (lds_cp)&Vl[buf][0];

        bf16x8 kb[4][2];
#pragma unroll
        for (int nk = 0; nk < 4; ++nk) {
            const int R = nk * 16 + l15;
            const int c0 = (g * 8) ^ ((R & 7) << 3);
            const lds_cp a0 = KB + R * 128 + c0 * 2;
            const lds_cp a1 = KB + R * 128 + (c0 ^ 32) * 2;
            DSR(kb[nk][0], a0, 0);
            DSR(kb[nk][1], a1, 0);
        }

        if (t < 15) stage(buf ^ 1, (t + 1) * 64);

        WAITLG;
        SCHEDB;

        f32x4 sc4[4];
#pragma unroll
        for (int nk = 0; nk < 4; ++nk) {
            f32x4 z = {};
            z = MFMA16(kb[nk][0], aq[0], z);
            z = MFMA16(kb[nk][1], aq[1], z);
            sc4[nk] = z;
        }

        float ml = sc4[0][0];
#pragma unroll
        for (int nk = 0; nk < 4; ++nk)
#pragma unroll
            for (int r = 0; r < 4; ++r) ml = fmaxf(ml, sc4[nk][r]);
        ml = fmaxf(ml, __shfl_xor(ml, 16));
        ml = fmaxf(ml, __shfl_xor(ml, 32));
        const float mn = fmaxf(m_run, ml);
        const float alpha = __expf(m_run - mn);
        m_run = mn;
        float padd[4][4];
        float rsum = 0.f;
#pragma unroll
        for (int nk = 0; nk < 4; ++nk)
#pragma unroll
            for (int r = 0; r < 4; ++r) {
                padd[nk][r] = __expf(sc4[nk][r] - mn);
                rsum += padd[nk][r];
            }
        rsum += __shfl_xor(rsum, 16);
        rsum += __shfl_xor(rsum, 32);
        l_run = l_run * alpha + rsum;
#pragma unroll
        for (int dn = 0; dn < 4; ++dn) o[dn] *= alpha;

#pragma unroll
        for (int nk = 0; nk < 4; ++nk) {
            unsigned u0, u1;
            CVTPK(u0, padd[nk][0], padd[nk][1]);
            CVTPK(u1, padd[nk][2], padd[nk][3]);
            const int cc = (nk * 16 + g * 4) ^ ((l15 & 7) << 3);
            uint2 uv; uv.x = u0; uv.y = u1;
            *reinterpret_cast<uint2*>(&Pl[w][l15 * 64 + cc]) = uv;
        }
        bf16x8 pa[2];
#pragma unroll
        for (int kk = 0; kk < 2; ++kk)
            pa[kk] = *(const bf16x8*)&Pl[w][l15 * 64 + ((kk * 32 + g * 8) ^ ((l15 & 7) << 3))];

        bf16x8 vb[4][2];
#pragma unroll
        for (int dn = 0; dn < 4; ++dn) {
            const int R = dn * 16 + l15;
            const int c0 = (g * 8) ^ ((R & 7) << 3);
            const lds_cp a0 = VB + R * 128 + c0 * 2;
            const lds_cp a1 = VB + R * 128 + (c0 ^ 32) * 2;
            DSR(vb[dn][0], a0, 0);
            DSR(vb[dn][1], a1, 0);
        }
        WAITLG;
        SCHEDB;

#pragma unroll
        for (int dn = 0; dn < 4; ++dn) {
            o[dn] = MFMA16(vb[dn][0], pa[0], o[dn]);
            o[dn] = MFMA16(vb[dn][1], pa[1], o[dn]);
        }

        __syncthreads();
        buf ^= 1;
    }

    const float rl = __builtin_amdgcn_rcpf(l_run);
    short* orow = out + ((size_t)(b * 1024) + q0 + l15) * 768 + h * 64;
#pragma unroll
    for (int dn = 0; dn < 4; ++dn) {
        unsigned u0, u1;
        const float v0 = o[dn][0] * rl, v1 = o[dn][1] * rl;
        const float v2 = o[dn][2] * rl, v3 = o[dn][3] * rl;
        CVTPK(u0, v0, v1);
        CVTPK(u1, v2, v3);
        uint2 uv; uv.x = u0; uv.y = u1;
        *reinterpret_cast<uint2*>(&orow[dn * 16 + g * 4]) = uv;
    }
}

// ---------------------------------------------------------------------------
// Launch
// ---------------------------------------------------------------------------
extern "C" void kernel_launch(void* const* d_in, const int* in_sizes, int n_in,
                              void* d_out, int out_size, void* d_ws, size_t ws_size,
                              hipStream_t stream) {
    const float* x      = (const float*)d_in[0];
    const float* ln1_g  = (const float*)d_in[1];
    const float* ln1_b  = (const float*)d_in[2];
    const float* qkv_w  = (const float*)d_in[3];
    const float* qkv_b  = (const float*)d_in[4];
    const float* proj_w = (const float*)d_in[5];
    const float* proj_b = (const float*)d_in[6];
    const float* ln2_g  = (const float*)d_in[7];
    const float* ln2_b  = (const float*)d_in[8];
    const float* fc1_w  = (const float*)d_in[9];
    const float* fc1_b  = (const float*)d_in[10];
    const float* fc2_w  = (const float*)d_in[11];
    const float* fc2_b  = (const float*)d_in[12];
    float* outp = (float*)d_out;

    char* ws = (char*)d_ws;
    size_t off = 0;
    auto alloc = [&](size_t bytes) {
        char* p = ws + off;
        off = (off + bytes + 255) & ~(size_t)255;
        return p;
    };
    short* wt_qkv  = (short*)alloc(2304ull * 768 * 2);
    short* wt_proj = (short*)alloc(768ull * 768 * 2);
    short* wt_fc1  = (short*)alloc(3072ull * 768 * 2);
    short* wt_fc2  = (short*)alloc(768ull * 3072 * 2);
    short* hbuf    = (short*)alloc(8192ull * 768 * 2);
    short* Qb      = (short*)alloc(8192ull * 768 * 2);   // [B,NH,S,HD]
    short* Kbuf    = (short*)alloc(8192ull * 768 * 2);   // [B,NH,S,HD]
    short* Vtb     = (short*)alloc(8192ull * 768 * 2);   // [B,NH,HD,S]
    short* attnb   = (short*)alloc(8192ull * 768 * 2);   // [B,S,H]
    float* x2      = (float*)alloc(8192ull * 768 * 4);   // fp32 residual stream
    short* mfc     = Qb;  // alias: fc1 output [8192,3072] over dead Q/K/Vt/attn
    (void)ws_size; (void)in_sizes; (void)n_in; (void)out_size;

    // weight prep
    transpose_w<<<dim3(2304 / 32, 768 / 32), 256, 0, stream>>>(qkv_w, wt_qkv, 768, 2304);
    transpose_w<<<dim3(768 / 32, 768 / 32), 256, 0, stream>>>(proj_w, wt_proj, 768, 768);
    transpose_w<<<dim3(3072 / 32, 768 / 32), 256, 0, stream>>>(fc1_w, wt_fc1, 768, 3072);
    transpose_w<<<dim3(768 / 32, 3072 / 32), 256, 0, stream>>>(fc2_w, wt_fc2, 3072, 768);

    // attention sublayer
    ln_k<<<8192, 256, 0, stream>>>(x, ln1_g, ln1_b, hbuf);
    gemmW<MODE_QKV><<<dim3(64, 9), 256, 0, stream>>>(
        hbuf, wt_qkv, qkv_b, nullptr, nullptr, nullptr, Qb, Kbuf, Vtb, 8192, 2304, 768);
    attn_k<<<1536, 256, 0, stream>>>(Qb, Kbuf, Vtb, attnb);
    gemm3p<MODE_F32RES><<<dim3(64, 6), 256, 0, stream>>>(
        attnb, wt_proj, proj_b, x, x2, nullptr, nullptr, nullptr, nullptr, 8192, 768, 768);

    // MLP sublayer
    ln_k<<<8192, 256, 0, stream>>>(x2, ln2_g, ln2_b, hbuf);
    gemmW<MODE_GELU><<<dim3(64, 12), 256, 0, stream>>>(
        hbuf, wt_fc1, fc1_b, nullptr, nullptr, mfc, nullptr, nullptr, nullptr, 8192, 3072, 768);
    gemm3p<MODE_F32RES><<<dim3(64, 6), 256, 0, stream>>>(
        mfc, wt_fc2, fc2_b, x2, outp, nullptr, nullptr, nullptr, nullptr, 8192, 768, 3072);
}

// Round 11
// 280.826 us; speedup vs baseline: 1.1662x; 1.1662x over previous
//
#include <hip/hip_runtime.h>
#include <hip/hip_bf16.h>

// ---------------------------------------------------------------------------
// Transformer block, B=8 S=1024 H=768 NH=12 HD=64 I=3072.  fp32 in/out,
// bf16 MFMA internals.
// Round 11: revert QKV/FC1 to gemm3p (gemmW died of AGPR+VGPR=272 -> 1
// wave/SIMD).  Fix gemm3p's LDS swizzle: old col16 ^= lane&3 left a 4-way
// bank conflict (rows r,r+8 alias; 4.2 extra cy/ds_read measured).  New
// placement: physical unit = R*4 + (cu ^ ((R>>1)&3)) -> 2-way (free).
// Applied to stage source permutation AND read offsets (rule 21).
// attn (swapped softmax, 0 conflicts) unchanged from round 8.
// ---------------------------------------------------------------------------

typedef __attribute__((ext_vector_type(8))) short bf16x8;
typedef __attribute__((ext_vector_type(4))) float f32x4;
typedef const __attribute__((address_space(3))) char* lds_cp;

#define MFMA16(a, b, c) __builtin_amdgcn_mfma_f32_16x16x32_bf16((a), (b), (c), 0, 0, 0)

// inline-asm LDS read: invisible to compiler alias analysis (no auto-vmcnt).
#define DSR(dst, addr, off) \
    asm volatile("ds_read_b128 %0, %1 offset:" #off : "=v"(dst) : "v"(addr))
#define WAITV4 asm volatile("s_waitcnt vmcnt(4)" ::: "memory")
#define WAITV0 asm volatile("s_waitcnt vmcnt(0)" ::: "memory")
#define WAITLG asm volatile("s_waitcnt lgkmcnt(0)" ::: "memory")
#define SCHEDB __builtin_amdgcn_sched_barrier(0)
// packed f32x2 -> bf16x2 (RNE), single instruction
#define CVTPK(d, lo, hi) \
    asm("v_cvt_pk_bf16_f32 %0, %1, %2" : "=v"(d) : "v"(lo), "v"(hi))

__device__ inline short f2bf(float x) {
    __hip_bfloat16 h = __float2bfloat16(x);
    return *reinterpret_cast<short*>(&h);
}

__device__ inline void gload_lds16(const void* g, void* lds) {
    __builtin_amdgcn_global_load_lds(
        (const __attribute__((address_space(1))) unsigned int*)g,
        (__attribute__((address_space(3))) unsigned int*)lds,
        16, 0, 0);
}

// ---------------------------------------------------------------------------
// Weight prep: W fp32 [K,N] -> Wt bf16 [N,K]   (tiled transpose + cast)
// ---------------------------------------------------------------------------
__global__ __launch_bounds__(256) void transpose_w(
    const float* __restrict__ W, short* __restrict__ Wt, int K, int N) {
    __shared__ float tile[32][33];
    const int tx = threadIdx.x & 31, ty = threadIdx.x >> 5;  // ty 0..7
    const int n0 = blockIdx.x * 32, k0 = blockIdx.y * 32;
#pragma unroll
    for (int i = 0; i < 4; ++i)
        tile[ty + i * 8][tx] = W[(size_t)(k0 + ty + i * 8) * N + n0 + tx];
    __syncthreads();
#pragma unroll
    for (int i = 0; i < 4; ++i)
        Wt[(size_t)(n0 + ty + i * 8) * K + k0 + tx] = f2bf(tile[tx][ty + i * 8]);
}

// ---------------------------------------------------------------------------
// LayerNorm: fp32 [M,768] -> bf16 [M,768]   (one block per row)
// ---------------------------------------------------------------------------
__global__ __launch_bounds__(256) void ln_k(
    const float* __restrict__ x, const float* __restrict__ g,
    const float* __restrict__ b, short* __restrict__ out) {
    const int row = blockIdx.x;
    const int tid = threadIdx.x;
    const float* xr = x + (size_t)row * 768;
    float v[3];
    float s = 0.f, sq = 0.f;
#pragma unroll
    for (int i = 0; i < 3; ++i) {
        v[i] = xr[tid + i * 256];
        s += v[i];
        sq += v[i] * v[i];
    }
#pragma unroll
    for (int off = 32; off >= 1; off >>= 1) {
        s += __shfl_xor(s, off);
        sq += __shfl_xor(sq, off);
    }
    __shared__ float ss[4], ssq[4];
    const int wid = tid >> 6;
    if ((tid & 63) == 0) { ss[wid] = s; ssq[wid] = sq; }
    __syncthreads();
    s = ss[0] + ss[1] + ss[2] + ss[3];
    sq = ssq[0] + ssq[1] + ssq[2] + ssq[3];
    const float mean = s * (1.0f / 768.0f);
    const float var = sq * (1.0f / 768.0f) - mean * mean;  // biased
    const float rstd = rsqrtf(var + 1e-5f);
    short* outr = out + (size_t)row * 768;
#pragma unroll
    for (int i = 0; i < 3; ++i) {
        const int c = tid + i * 256;
        outr[c] = f2bf((v[i] - mean) * rstd * g[c] + b[c]);
    }
}

enum { MODE_BF16 = 0, MODE_QKV = 1, MODE_F32RES = 2, MODE_GELU = 3 };

// ---------------------------------------------------------------------------
// Epilogue writer.
// ---------------------------------------------------------------------------
template <int MODE>
__device__ inline void epi_store(
    float v, int row, int col, int N,
    const float* __restrict__ resid, float* __restrict__ outf,
    short* __restrict__ outh, short* __restrict__ Qo,
    short* __restrict__ Ko, short* __restrict__ Vto) {
    if constexpr (MODE == MODE_BF16) {
        outh[(size_t)row * N + col] = f2bf(v);
    } else if constexpr (MODE == MODE_GELU) {
        // 0.5v(1+tanh(u)) == v*sigmoid(2u)
        const float u = 0.7978845608028654f * (v + 0.044715f * v * v * v);
        const float gl = v / (1.0f + __expf(-2.0f * u));
        outh[(size_t)row * N + col] = f2bf(gl);
    } else if constexpr (MODE == MODE_F32RES) {
        outf[(size_t)row * N + col] = v + resid[(size_t)row * N + col];
    } else {  // MODE_QKV: Q pre-scaled by 1/8; K; V transposed
        const int bb = row >> 10, s = row & 1023;
        if (col < 768) {
            const int hh = col >> 6, d = col & 63;
            Qo[(((size_t)(bb * 12 + hh)) * 1024 + s) * 64 + d] = f2bf(v * 0.125f);
        } else if (col < 1536) {
            const int c2 = col - 768;
            const int hh = c2 >> 6, d = c2 & 63;
            Ko[(((size_t)(bb * 12 + hh)) * 1024 + s) * 64 + d] = f2bf(v);
        } else {
            const int c2 = col - 1536;
            const int hh = c2 >> 6, d = c2 & 63;
            Vto[(((size_t)(bb * 12 + hh)) * 64 + d) * 1024 + s] = f2bf(v);
        }
    }
}

// ---------------------------------------------------------------------------
// gemm3p: 128x128 tile, BK=32, 3 LDS buffers, counted vmcnt(4), 2 barriers
// per K-tile.  LDS placement: logical (row R, 16B-unit cu) at physical unit
// R*4 + (cu ^ ((R>>1)&3))  -> wave frag reads are 2-way (free) not 4-way.
// ---------------------------------------------------------------------------
template <int MODE>
__global__ __launch_bounds__(256) void gemm3p(
    const short* __restrict__ A, const short* __restrict__ Wt,
    const float* __restrict__ bias, const float* __restrict__ resid,
    float* __restrict__ outf, short* __restrict__ outh,
    short* __restrict__ Qo, short* __restrict__ Ko, short* __restrict__ Vto,
    int M, int N, int K) {
    __shared__ __attribute__((aligned(128))) short Al[3][4096];
    __shared__ __attribute__((aligned(128))) short Bl[3][4096];
    const int tid = threadIdx.x;
    const int lane = tid & 63;
    const int w = tid >> 6;
    const int wm = w >> 1, wn = w & 1;
    const int m0 = blockIdx.x * 128, n0 = blockIdx.y * 128;

    f32x4 acc[4][4] = {};

    // staging: thread tid fills physical unit tid (linear dest).  Its logical
    // source: row R = tid>>2, unit cu = (tid&3) ^ ((R>>1)&3) = (tid&3)^((tid>>3)&3).
    const int srow = tid >> 2;
    const int scol = (((tid & 3) ^ ((tid >> 3) & 3)) * 8);
    const short* Abase = A + (size_t)(m0 + srow) * K + scol;
    const short* Bbase = Wt + (size_t)(n0 + srow) * K + scol;
    const size_t K64 = (size_t)K * 64;
    short* const AlF = &Al[0][0];
    short* const BlF = &Bl[0][0];

    auto stageT = [&](int boS, int k0s) {
        gload_lds16(Abase + k0s,       AlF + boS + w * 512);
        gload_lds16(Abase + K64 + k0s, AlF + boS + 2048 + w * 512);
        gload_lds16(Bbase + k0s,       BlF + boS + w * 512);
        gload_lds16(Bbase + K64 + k0s, BlF + boS + 2048 + w * 512);
    };

    // fragment read: lane wants logical (R = l15 (+16*mi via offset), cu = g)
    // -> physical byte R*64 + (g ^ ((R>>1)&3))*16.  16*mi keeps (R>>1)&3
    // invariant, so the mi*1024 offset immediates stay valid.
    const int l15 = lane & 15, g = lane >> 4;
    const int lcolswz = (g ^ ((l15 >> 1) & 3)) << 4;
    const int aoff = wm * 4096 + l15 * 64 + lcolswz;
    const int boff = wn * 4096 + l15 * 64 + lcolswz;
    const lds_cp AlB = (lds_cp)AlF;
    const lds_cp BlB = (lds_cp)BlF;

    const int NT = K >> 5;

    stageT(0, 0);
    stageT(4096, 32);
    WAITV4;
    SCHEDB;
    __builtin_amdgcn_s_barrier();

    int bo = 0, bo1 = 8192, bo2 = 16384;
    for (int t = 0; t < NT; ++t) {
        const lds_cp Ab = AlB + (bo + aoff);
        const lds_cp Bb = BlB + (bo + boff);
        bf16x8 av0, av1, av2, av3, bv0, bv1, bv2, bv3;
        DSR(av0, Ab, 0);
        DSR(av1, Ab, 1024);
        DSR(av2, Ab, 2048);
        DSR(av3, Ab, 3072);
        DSR(bv0, Bb, 0);
        DSR(bv1, Bb, 1024);
        DSR(bv2, Bb, 2048);
        DSR(bv3, Bb, 3072);

        int ts = t + 2;
        if (ts > NT - 1) ts = NT - 1;
        stageT(bo2 >> 1, ts << 5);
        WAITV4;
        SCHEDB;
        __builtin_amdgcn_s_barrier();
        WAITLG;
        SCHEDB;

        __builtin_amdgcn_s_setprio(1);
        {
            bf16x8 av[4] = {av0, av1, av2, av3};
            bf16x8 bv[4] = {bv0, bv1, bv2, bv3};
#pragma unroll
            for (int mi = 0; mi < 4; ++mi)
#pragma unroll
                for (int ni = 0; ni < 4; ++ni)
                    acc[mi][ni] = MFMA16(av[mi], bv[ni], acc[mi][ni]);
        }
        __builtin_amdgcn_s_setprio(0);
        __builtin_amdgcn_s_barrier();

        const int tmp = bo; bo = bo1; bo1 = bo2; bo2 = tmp;
    }
    WAITV0;

#pragma unroll
    for (int mi = 0; mi < 4; ++mi)
#pragma unroll
        for (int ni = 0; ni < 4; ++ni)
#pragma unroll
            for (int r = 0; r < 4; ++r) {
                const int row = m0 + wm * 64 + mi * 16 + (lane >> 4) * 4 + r;
                const int col = n0 + wn * 64 + ni * 16 + (lane & 15);
                epi_store<MODE>(acc[mi][ni][r] + bias[col], row, col, N,
                                resid, outf, outh, Qo, Ko, Vto);
            }
}

// ---------------------------------------------------------------------------
// Flash attention, swapped-operand softmax (unchanged from round 8).
// ---------------------------------------------------------------------------
__global__ __launch_bounds__(256) void attn_k(
    const short* __restrict__ Q, const short* __restrict__ Kg,
    const short* __restrict__ Vtg, short* __restrict__ out) {
    __shared__ __attribute__((aligned(128))) short Kl[2][64 * 64];
    __shared__ __attribute__((aligned(128))) short Vl[2][64 * 64];
    __shared__ __attribute__((aligned(128))) short Pl[4][16 * 64];
    const int tid = threadIdx.x, lane = tid & 63, w = tid >> 6;
    const int swz = (blockIdx.x & 7) * 192 + (blockIdx.x >> 3);
    const int qt = swz & 15, bh = swz >> 4;
    const int b = bh / 12, h = bh % 12;
    const int q0 = qt * 64 + w * 16;
    const int l15 = lane & 15, g = lane >> 4;

    bf16x8 aq[2];
    const short* Qb = Q + ((size_t)bh * 1024 + q0) * 64;
#pragma unroll
    for (int kk = 0; kk < 2; ++kk)
        aq[kk] = *(const bf16x8*)&Qb[(size_t)l15 * 64 + kk * 32 + g * 8];

    float m_run = -1e30f, l_run = 0.f;
    f32x4 o[4] = {};

    const short* Kb = Kg + (size_t)bh * 1024 * 64;
    const short* Vb = Vtg + (size_t)bh * 64 * 1024;

    const int srr = tid >> 3;
    const int spp = (tid & 7) * 8;
    const int ssc = spp ^ ((srr & 7) << 3);
    auto stage = [&](int buf, int kv0) {
        gload_lds16(Kb + (size_t)(kv0 + srr) * 64 + ssc,        &Kl[buf][w * 512]);
        gload_lds16(Kb + (size_t)(kv0 + 32 + srr) * 64 + ssc,   &Kl[buf][2048 + w * 512]);
        gload_lds16(Vb + (size_t)srr * 1024 + kv0 + ssc,        &Vl[buf][w * 512]);
        gload_lds16(Vb + (size_t)(srr + 32) * 1024 + kv0 + ssc, &Vl[buf][2048 + w * 512]);
    };

    stage(0, 0);
    __syncthreads();

    int buf = 0;
    for (int t = 0; t < 16; ++t) {
        const lds_cp KB = (lds_cp)&Kl[buf][0];
        const lds_cp VB = (lds_cp)&Vl[buf][0];

        bf16x8 kb[4][2];
#pragma unroll
        for (int nk = 0; nk < 4; ++nk) {
            const int R = nk * 16 + l15;
            const int c0 = (g * 8) ^ ((R & 7) << 3);
            const lds_cp a0 = KB + R * 128 + c0 * 2;
            const lds_cp a1 = KB + R * 128 + (c0 ^ 32) * 2;
            DSR(kb[nk][0], a0, 0);
            DSR(kb[nk][1], a1, 0);
        }

        if (t < 15) stage(buf ^ 1, (t + 1) * 64);

        WAITLG;
        SCHEDB;

        f32x4 sc4[4];
#pragma unroll
        for (int nk = 0; nk < 4; ++nk) {
            f32x4 z = {};
            z = MFMA16(kb[nk][0], aq[0], z);
            z = MFMA16(kb[nk][1], aq[1], z);
            sc4[nk] = z;
        }

        float ml = sc4[0][0];
#pragma unroll
        for (int nk = 0; nk < 4; ++nk)
#pragma unroll
            for (int r = 0; r < 4; ++r) ml = fmaxf(ml, sc4[nk][r]);
        ml = fmaxf(ml, __shfl_xor(ml, 16));
        ml = fmaxf(ml, __shfl_xor(ml, 32));
        const float mn = fmaxf(m_run, ml);
        const float alpha = __expf(m_run - mn);
        m_run = mn;
        float padd[4][4];
        float rsum = 0.f;
#pragma unroll
        for (int nk = 0; nk < 4; ++nk)
#pragma unroll
            for (int r = 0; r < 4; ++r) {
                padd[nk][r] = __expf(sc4[nk][r] - mn);
                rsum += padd[nk][r];
            }
        rsum += __shfl_xor(rsum, 16);
        rsum += __shfl_xor(rsum, 32);
        l_run = l_run * alpha + rsum;
#pragma unroll
        for (int dn = 0; dn < 4; ++dn) o[dn] *= alpha;

#pragma unroll
        for (int nk = 0; nk < 4; ++nk) {
            unsigned u0, u1;
            CVTPK(u0, padd[nk][0], padd[nk][1]);
            CVTPK(u1, padd[nk][2], padd[nk][3]);
            const int cc = (nk * 16 + g * 4) ^ ((l15 & 7) << 3);
            uint2 uv; uv.x = u0; uv.y = u1;
            *reinterpret_cast<uint2*>(&Pl[w][l15 * 64 + cc]) = uv;
        }
        bf16x8 pa[2];
#pragma unroll
        for (int kk = 0; kk < 2; ++kk)
            pa[kk] = *(const bf16x8*)&Pl[w][l15 * 64 + ((kk * 32 + g * 8) ^ ((l15 & 7) << 3))];

        bf16x8 vb[4][2];
#pragma unroll
        for (int dn = 0; dn < 4; ++dn) {
            const int R = dn * 16 + l15;
            const int c0 = (g * 8) ^ ((R & 7) << 3);
            const lds_cp a0 = VB + R * 128 + c0 * 2;
            const lds_cp a1 = VB + R * 128 + (c0 ^ 32) * 2;
            DSR(vb[dn][0], a0, 0);
            DSR(vb[dn][1], a1, 0);
        }
        WAITLG;
        SCHEDB;

#pragma unroll
        for (int dn = 0; dn < 4; ++dn) {
            o[dn] = MFMA16(vb[dn][0], pa[0], o[dn]);
            o[dn] = MFMA16(vb[dn][1], pa[1], o[dn]);
        }

        __syncthreads();
        buf ^= 1;
    }

    const float rl = __builtin_amdgcn_rcpf(l_run);
    short* orow = out + ((size_t)(b * 1024) + q0 + l15) * 768 + h * 64;
#pragma unroll
    for (int dn = 0; dn < 4; ++dn) {
        unsigned u0, u1;
        const float v0 = o[dn][0] * rl, v1 = o[dn][1] * rl;
        const float v2 = o[dn][2] * rl, v3 = o[dn][3] * rl;
        CVTPK(u0, v0, v1);
        CVTPK(u1, v2, v3);
        uint2 uv; uv.x = u0; uv.y = u1;
        *reinterpret_cast<uint2*>(&orow[dn * 16 + g * 4]) = uv;
    }
}

// ---------------------------------------------------------------------------
// Launch
// ---------------------------------------------------------------------------
extern "C" void kernel_launch(void* const* d_in, const int* in_sizes, int n_in,
                              void* d_out, int out_size, void* d_ws, size_t ws_size,
                              hipStream_t stream) {
    const float* x      = (const float*)d_in[0];
    const float* ln1_g  = (const float*)d_in[1];
    const float* ln1_b  = (const float*)d_in[2];
    const float* qkv_w  = (const float*)d_in[3];
    const float* qkv_b  = (const float*)d_in[4];
    const float* proj_w = (const float*)d_in[5];
    const float* proj_b = (const float*)d_in[6];
    const float* ln2_g  = (const float*)d_in[7];
    const float* ln2_b  = (const float*)d_in[8];
    const float* fc1_w  = (const float*)d_in[9];
    const float* fc1_b  = (const float*)d_in[10];
    const float* fc2_w  = (const float*)d_in[11];
    const float* fc2_b  = (const float*)d_in[12];
    float* outp = (float*)d_out;

    char* ws = (char*)d_ws;
    size_t off = 0;
    auto alloc = [&](size_t bytes) {
        char* p = ws + off;
        off = (off + bytes + 255) & ~(size_t)255;
        return p;
    };
    short* wt_qkv  = (short*)alloc(2304ull * 768 * 2);
    short* wt_proj = (short*)alloc(768ull * 768 * 2);
    short* wt_fc1  = (short*)alloc(3072ull * 768 * 2);
    short* wt_fc2  = (short*)alloc(768ull * 3072 * 2);
    short* hbuf    = (short*)alloc(8192ull * 768 * 2);
    short* Qb      = (short*)alloc(8192ull * 768 * 2);   // [B,NH,S,HD]
    short* Kbuf    = (short*)alloc(8192ull * 768 * 2);   // [B,NH,S,HD]
    short* Vtb     = (short*)alloc(8192ull * 768 * 2);   // [B,NH,HD,S]
    short* attnb   = (short*)alloc(8192ull * 768 * 2);   // [B,S,H]
    float* x2      = (float*)alloc(8192ull * 768 * 4);   // fp32 residual stream
    short* mfc     = Qb;  // alias: fc1 output [8192,3072] over dead Q/K/Vt/attn
    (void)ws_size; (void)in_sizes; (void)n_in; (void)out_size;

    // weight prep
    transpose_w<<<dim3(2304 / 32, 768 / 32), 256, 0, stream>>>(qkv_w, wt_qkv, 768, 2304);
    transpose_w<<<dim3(768 / 32, 768 / 32), 256, 0, stream>>>(proj_w, wt_proj, 768, 768);
    transpose_w<<<dim3(3072 / 32, 768 / 32), 256, 0, stream>>>(fc1_w, wt_fc1, 768, 3072);
    transpose_w<<<dim3(768 / 32, 3072 / 32), 256, 0, stream>>>(fc2_w, wt_fc2, 3072, 768);

    // attention sublayer
    ln_k<<<8192, 256, 0, stream>>>(x, ln1_g, ln1_b, hbuf);
    gemm3p<MODE_QKV><<<dim3(64, 18), 256, 0, stream>>>(
        hbuf, wt_qkv, qkv_b, nullptr, nullptr, nullptr, Qb, Kbuf, Vtb, 8192, 2304, 768);
    attn_k<<<1536, 256, 0, stream>>>(Qb, Kbuf, Vtb, attnb);
    gemm3p<MODE_F32RES><<<dim3(64, 6), 256, 0, stream>>>(
        attnb, wt_proj, proj_b, x, x2, nullptr, nullptr, nullptr, nullptr, 8192, 768, 768);

    // MLP sublayer
    ln_k<<<8192, 256, 0, stream>>>(x2, ln2_g, ln2_b, hbuf);
    gemm3p<MODE_GELU><<<dim3(64, 24), 256, 0, stream>>>(
        hbuf, wt_fc1, fc1_b, nullptr, nullptr, mfc, nullptr, nullptr, nullptr, 8192, 3072, 768);
    gemm3p<MODE_F32RES><<<dim3(64, 6), 256, 0, stream>>>(
        mfc, wt_fc2, fc2_b, x2, outp, nullptr, nullptr, nullptr, nullptr, 8192, 768, 3072);
}

// Round 12
// 277.604 us; speedup vs baseline: 1.1797x; 1.0116x over previous
//
#include <hip/hip_runtime.h>
#include <hip/hip_bf16.h>

// ---------------------------------------------------------------------------
// Transformer block, B=8 S=1024 H=768 NH=12 HD=64 I=3072.  fp32 in/out,
// bf16 MFMA internals.
// Round 12: GEMM operand-swap epilogue -- mfma(Wt_frag, A_frag) makes each
// thread own C[m][n..n+3] (4 consecutive n), so: bias = 1 float4 load,
// F32RES = float4 residual load + float4 store, GELU/QKV = cvt_pk + 8B
// stores (was 64 scalar stores/loads per thread).  Main loop unchanged.
// ln_k vectorized: 192 thr, float4 loads, packed uint2 stores (G13).
// attn / staging / swizzles unchanged from round 11.
// ---------------------------------------------------------------------------

typedef __attribute__((ext_vector_type(8))) short bf16x8;
typedef __attribute__((ext_vector_type(4))) float f32x4;
typedef const __attribute__((address_space(3))) char* lds_cp;

#define MFMA16(a, b, c) __builtin_amdgcn_mfma_f32_16x16x32_bf16((a), (b), (c), 0, 0, 0)

// inline-asm LDS read: invisible to compiler alias analysis (no auto-vmcnt).
#define DSR(dst, addr, off) \
    asm volatile("ds_read_b128 %0, %1 offset:" #off : "=v"(dst) : "v"(addr))
#define WAITV4 asm volatile("s_waitcnt vmcnt(4)" ::: "memory")
#define WAITV0 asm volatile("s_waitcnt vmcnt(0)" ::: "memory")
#define WAITLG asm volatile("s_waitcnt lgkmcnt(0)" ::: "memory")
#define SCHEDB __builtin_amdgcn_sched_barrier(0)
// packed f32x2 -> bf16x2 (RNE), single instruction; low short = first src
#define CVTPK(d, lo, hi) \
    asm("v_cvt_pk_bf16_f32 %0, %1, %2" : "=v"(d) : "v"(lo), "v"(hi))

__device__ inline short f2bf(float x) {
    __hip_bfloat16 h = __float2bfloat16(x);
    return *reinterpret_cast<short*>(&h);
}

__device__ inline void gload_lds16(const void* g, void* lds) {
    __builtin_amdgcn_global_load_lds(
        (const __attribute__((address_space(1))) unsigned int*)g,
        (__attribute__((address_space(3))) unsigned int*)lds,
        16, 0, 0);
}

// ---------------------------------------------------------------------------
// Weight prep: W fp32 [K,N] -> Wt bf16 [N,K]   (tiled transpose + cast)
// ---------------------------------------------------------------------------
__global__ __launch_bounds__(256) void transpose_w(
    const float* __restrict__ W, short* __restrict__ Wt, int K, int N) {
    __shared__ float tile[32][33];
    const int tx = threadIdx.x & 31, ty = threadIdx.x >> 5;  // ty 0..7
    const int n0 = blockIdx.x * 32, k0 = blockIdx.y * 32;
#pragma unroll
    for (int i = 0; i < 4; ++i)
        tile[ty + i * 8][tx] = W[(size_t)(k0 + ty + i * 8) * N + n0 + tx];
    __syncthreads();
#pragma unroll
    for (int i = 0; i < 4; ++i)
        Wt[(size_t)(n0 + ty + i * 8) * K + k0 + tx] = f2bf(tile[tx][ty + i * 8]);
}

// ---------------------------------------------------------------------------
// LayerNorm: fp32 [M,768] -> bf16 [M,768].  192 threads/row, float4 loads,
// packed uint2 stores.
// ---------------------------------------------------------------------------
__global__ __launch_bounds__(192) void ln_k(
    const float* __restrict__ x, const float* __restrict__ g,
    const float* __restrict__ b, short* __restrict__ out) {
    const int row = blockIdx.x;
    const int tid = threadIdx.x;
    const float4 v = *reinterpret_cast<const float4*>(&x[(size_t)row * 768 + tid * 4]);
    float s = v.x + v.y + v.z + v.w;
    float sq = v.x * v.x + v.y * v.y + v.z * v.z + v.w * v.w;
#pragma unroll
    for (int off = 32; off >= 1; off >>= 1) {
        s += __shfl_xor(s, off);
        sq += __shfl_xor(sq, off);
    }
    __shared__ float ss[3], ssq[3];
    const int wid = tid >> 6;
    if ((tid & 63) == 0) { ss[wid] = s; ssq[wid] = sq; }
    __syncthreads();
    s = ss[0] + ss[1] + ss[2];
    sq = ssq[0] + ssq[1] + ssq[2];
    const float mean = s * (1.0f / 768.0f);
    const float var = sq * (1.0f / 768.0f) - mean * mean;  // biased
    const float rstd = rsqrtf(var + 1e-5f);
    const float4 gg = *reinterpret_cast<const float4*>(&g[tid * 4]);
    const float4 bb = *reinterpret_cast<const float4*>(&b[tid * 4]);
    const float r0 = (v.x - mean) * rstd * gg.x + bb.x;
    const float r1 = (v.y - mean) * rstd * gg.y + bb.y;
    const float r2 = (v.z - mean) * rstd * gg.z + bb.z;
    const float r3 = (v.w - mean) * rstd * gg.w + bb.w;
    unsigned u0, u1;
    CVTPK(u0, r0, r1);
    CVTPK(u1, r2, r3);
    uint2 uv; uv.x = u0; uv.y = u1;
    *reinterpret_cast<uint2*>(&out[(size_t)row * 768 + tid * 4]) = uv;
}

enum { MODE_BF16 = 0, MODE_QKV = 1, MODE_F32RES = 2, MODE_GELU = 3 };

// ---------------------------------------------------------------------------
// Packed 4-wide epilogue: thread owns C[mrow][nbase..nbase+3].
// ---------------------------------------------------------------------------
template <int MODE>
__device__ inline void epi_store4(
    const float* v4, int mrow, int nbase, int N,
    const float* __restrict__ resid, float* __restrict__ outf,
    short* __restrict__ outh, short* __restrict__ Qo,
    short* __restrict__ Ko, short* __restrict__ Vto) {
    if constexpr (MODE == MODE_BF16) {
        unsigned u0, u1;
        CVTPK(u0, v4[0], v4[1]);
        CVTPK(u1, v4[2], v4[3]);
        uint2 uv; uv.x = u0; uv.y = u1;
        *reinterpret_cast<uint2*>(&outh[(size_t)mrow * N + nbase]) = uv;
    } else if constexpr (MODE == MODE_GELU) {
        float gl[4];
#pragma unroll
        for (int r = 0; r < 4; ++r) {
            const float vv = v4[r];
            const float u = 0.7978845608028654f * (vv + 0.044715f * vv * vv * vv);
            gl[r] = vv / (1.0f + __expf(-2.0f * u));
        }
        unsigned u0, u1;
        CVTPK(u0, gl[0], gl[1]);
        CVTPK(u1, gl[2], gl[3]);
        uint2 uv; uv.x = u0; uv.y = u1;
        *reinterpret_cast<uint2*>(&outh[(size_t)mrow * N + nbase]) = uv;
    } else if constexpr (MODE == MODE_F32RES) {
        const float4 rs = *reinterpret_cast<const float4*>(&resid[(size_t)mrow * N + nbase]);
        float4 o4;
        o4.x = v4[0] + rs.x;
        o4.y = v4[1] + rs.y;
        o4.z = v4[2] + rs.z;
        o4.w = v4[3] + rs.w;
        *reinterpret_cast<float4*>(&outf[(size_t)mrow * N + nbase]) = o4;
    } else {  // MODE_QKV
        const int bb = mrow >> 10, s = mrow & 1023;
        if (nbase < 768) {
            const int hh = nbase >> 6, d = nbase & 63;
            unsigned u0, u1;
            CVTPK(u0, v4[0] * 0.125f, v4[1] * 0.125f);
            CVTPK(u1, v4[2] * 0.125f, v4[3] * 0.125f);
            uint2 uv; uv.x = u0; uv.y = u1;
            *reinterpret_cast<uint2*>(
                &Qo[(((size_t)(bb * 12 + hh)) * 1024 + s) * 64 + d]) = uv;
        } else if (nbase < 1536) {
            const int c2 = nbase - 768;
            const int hh = c2 >> 6, d = c2 & 63;
            unsigned u0, u1;
            CVTPK(u0, v4[0], v4[1]);
            CVTPK(u1, v4[2], v4[3]);
            uint2 uv; uv.x = u0; uv.y = u1;
            *reinterpret_cast<uint2*>(
                &Ko[(((size_t)(bb * 12 + hh)) * 1024 + s) * 64 + d]) = uv;
        } else {
            const int c2 = nbase - 1536;
            const int hh = c2 >> 6, d = c2 & 63;
#pragma unroll
            for (int r = 0; r < 4; ++r)
                Vto[(((size_t)(bb * 12 + hh)) * 64 + d + r) * 1024 + s] = f2bf(v4[r]);
        }
    }
}

// ---------------------------------------------------------------------------
// gemm3p: 128x128 tile, BK=32, 3 LDS buffers, counted vmcnt(4), 2 barriers
// per K-tile.  LDS placement: logical (row R, 16B-unit cu) at physical unit
// R*4 + (cu ^ ((R>>1)&3))  (2-way, conflict-free -- verified 0 in r11).
// MFMA operand-swapped: D col = m (lane&15), D rows = 4 consecutive n.
// ---------------------------------------------------------------------------
template <int MODE>
__global__ __launch_bounds__(256) void gemm3p(
    const short* __restrict__ A, const short* __restrict__ Wt,
    const float* __restrict__ bias, const float* __restrict__ resid,
    float* __restrict__ outf, short* __restrict__ outh,
    short* __restrict__ Qo, short* __restrict__ Ko, short* __restrict__ Vto,
    int M, int N, int K) {
    __shared__ __attribute__((aligned(128))) short Al[3][4096];
    __shared__ __attribute__((aligned(128))) short Bl[3][4096];
    const int tid = threadIdx.x;
    const int lane = tid & 63;
    const int w = tid >> 6;
    const int wm = w >> 1, wn = w & 1;
    const int m0 = blockIdx.x * 128, n0 = blockIdx.y * 128;

    f32x4 acc[4][4] = {};

    // staging: thread tid fills physical unit tid (linear dest); logical
    // source unit cu = (tid&3) ^ ((tid>>3)&3).
    const int srow = tid >> 2;
    const int scol = (((tid & 3) ^ ((tid >> 3) & 3)) * 8);
    const short* Abase = A + (size_t)(m0 + srow) * K + scol;
    const short* Bbase = Wt + (size_t)(n0 + srow) * K + scol;
    const size_t K64 = (size_t)K * 64;
    short* const AlF = &Al[0][0];
    short* const BlF = &Bl[0][0];

    auto stageT = [&](int boS, int k0s) {
        gload_lds16(Abase + k0s,       AlF + boS + w * 512);
        gload_lds16(Abase + K64 + k0s, AlF + boS + 2048 + w * 512);
        gload_lds16(Bbase + k0s,       BlF + boS + w * 512);
        gload_lds16(Bbase + K64 + k0s, BlF + boS + 2048 + w * 512);
    };

    // fragment read: logical (R = l15 + 16*mi, cu = g) at physical byte
    // R*64 + (g ^ ((R>>1)&3))*16; 16*mi preserves the swizzle bits.
    const int l15 = lane & 15, g = lane >> 4;
    const int lcolswz = (g ^ ((l15 >> 1) & 3)) << 4;
    const int aoff = wm * 4096 + l15 * 64 + lcolswz;
    const int boff = wn * 4096 + l15 * 64 + lcolswz;
    const lds_cp AlB = (lds_cp)AlF;
    const lds_cp BlB = (lds_cp)BlF;

    const int NT = K >> 5;

    stageT(0, 0);
    stageT(4096, 32);
    WAITV4;
    SCHEDB;
    __builtin_amdgcn_s_barrier();

    int bo = 0, bo1 = 8192, bo2 = 16384;
    for (int t = 0; t < NT; ++t) {
        const lds_cp Ab = AlB + (bo + aoff);
        const lds_cp Bb = BlB + (bo + boff);
        bf16x8 av0, av1, av2, av3, bv0, bv1, bv2, bv3;
        DSR(av0, Ab, 0);
        DSR(av1, Ab, 1024);
        DSR(av2, Ab, 2048);
        DSR(av3, Ab, 3072);
        DSR(bv0, Bb, 0);
        DSR(bv1, Bb, 1024);
        DSR(bv2, Bb, 2048);
        DSR(bv3, Bb, 3072);

        int ts = t + 2;
        if (ts > NT - 1) ts = NT - 1;
        stageT(bo2 >> 1, ts << 5);
        WAITV4;
        SCHEDB;
        __builtin_amdgcn_s_barrier();
        WAITLG;
        SCHEDB;

        __builtin_amdgcn_s_setprio(1);
        {
            bf16x8 av[4] = {av0, av1, av2, av3};
            bf16x8 bv[4] = {bv0, bv1, bv2, bv3};
#pragma unroll
            for (int mi = 0; mi < 4; ++mi)
#pragma unroll
                for (int ni = 0; ni < 4; ++ni)
                    acc[mi][ni] = MFMA16(bv[ni], av[mi], acc[mi][ni]);  // swapped
        }
        __builtin_amdgcn_s_setprio(0);
        __builtin_amdgcn_s_barrier();

        const int tmp = bo; bo = bo1; bo1 = bo2; bo2 = tmp;
    }
    WAITV0;

    // Epilogue: swapped D layout -> thread owns C[mrow][nbase..nbase+3].
#pragma unroll
    for (int ni = 0; ni < 4; ++ni) {
        const int nbase = n0 + wn * 64 + ni * 16 + g * 4;
        const float4 b4 = *reinterpret_cast<const float4*>(&bias[nbase]);
#pragma unroll
        for (int mi = 0; mi < 4; ++mi) {
            const int mrow = m0 + wm * 64 + mi * 16 + l15;
            float v4[4] = {acc[mi][ni][0] + b4.x, acc[mi][ni][1] + b4.y,
                           acc[mi][ni][2] + b4.z, acc[mi][ni][3] + b4.w};
            epi_store4<MODE>(v4, mrow, nbase, N, resid, outf, outh, Qo, Ko, Vto);
        }
    }
}

// ---------------------------------------------------------------------------
// Flash attention, swapped-operand softmax (unchanged from round 8).
// ---------------------------------------------------------------------------
__global__ __launch_bounds__(256) void attn_k(
    const short* __restrict__ Q, const short* __restrict__ Kg,
    const short* __restrict__ Vtg, short* __restrict__ out) {
    __shared__ __attribute__((aligned(128))) short Kl[2][64 * 64];
    __shared__ __attribute__((aligned(128))) short Vl[2][64 * 64];
    __shared__ __attribute__((aligned(128))) short Pl[4][16 * 64];
    const int tid = threadIdx.x, lane = tid & 63, w = tid >> 6;
    const int swz = (blockIdx.x & 7) * 192 + (blockIdx.x >> 3);
    const int qt = swz & 15, bh = swz >> 4;
    const int b = bh / 12, h = bh % 12;
    const int q0 = qt * 64 + w * 16;
    const int l15 = lane & 15, g = lane >> 4;

    bf16x8 aq[2];
    const short* Qb = Q + ((size_t)bh * 1024 + q0) * 64;
#pragma unroll
    for (int kk = 0; kk < 2; ++kk)
        aq[kk] = *(const bf16x8*)&Qb[(size_t)l15 * 64 + kk * 32 + g * 8];

    float m_run = -1e30f, l_run = 0.f;
    f32x4 o[4] = {};

    const short* Kb = Kg + (size_t)bh * 1024 * 64;
    const short* Vb = Vtg + (size_t)bh * 64 * 1024;

    const int srr = tid >> 3;
    const int spp = (tid & 7) * 8;
    const int ssc = spp ^ ((srr & 7) << 3);
    auto stage = [&](int buf, int kv0) {
        gload_lds16(Kb + (size_t)(kv0 + srr) * 64 + ssc,        &Kl[buf][w * 512]);
        gload_lds16(Kb + (size_t)(kv0 + 32 + srr) * 64 + ssc,   &Kl[buf][2048 + w * 512]);
        gload_lds16(Vb + (size_t)srr * 1024 + kv0 + ssc,        &Vl[buf][w * 512]);
        gload_lds16(Vb + (size_t)(srr + 32) * 1024 + kv0 + ssc, &Vl[buf][2048 + w * 512]);
    };

    stage(0, 0);
    __syncthreads();

    int buf = 0;
    for (int t = 0; t < 16; ++t) {
        const lds_cp KB = (lds_cp)&Kl[buf][0];
        const lds_cp VB = (lds_cp)&Vl[buf][0];

        bf16x8 kb[4][2];
#pragma unroll
        for (int nk = 0; nk < 4; ++nk) {
            const int R = nk * 16 + l15;
            const int c0 = (g * 8) ^ ((R & 7) << 3);
            const lds_cp a0 = KB + R * 128 + c0 * 2;
            const lds_cp a1 = KB + R * 128 + (c0 ^ 32) * 2;
            DSR(kb[nk][0], a0, 0);
            DSR(kb[nk][1], a1, 0);
        }

        if (t < 15) stage(buf ^ 1, (t + 1) * 64);

        WAITLG;
        SCHEDB;

        f32x4 sc4[4];
#pragma unroll
        for (int nk = 0; nk < 4; ++nk) {
            f32x4 z = {};
            z = MFMA16(kb[nk][0], aq[0], z);
            z = MFMA16(kb[nk][1], aq[1], z);
            sc4[nk] = z;
        }

        float ml = sc4[0][0];
#pragma unroll
        for (int nk = 0; nk < 4; ++nk)
#pragma unroll
            for (int r = 0; r < 4; ++r) ml = fmaxf(ml, sc4[nk][r]);
        ml = fmaxf(ml, __shfl_xor(ml, 16));
        ml = fmaxf(ml, __shfl_xor(ml, 32));
        const float mn = fmaxf(m_run, ml);
        const float alpha = __expf(m_run - mn);
        m_run = mn;
        float padd[4][4];
        float rsum = 0.f;
#pragma unroll
        for (int nk = 0; nk < 4; ++nk)
#pragma unroll
            for (int r = 0; r < 4; ++r) {
                padd[nk][r] = __expf(sc4[nk][r] - mn);
                rsum += padd[nk][r];
            }
        rsum += __shfl_xor(rsum, 16);
        rsum += __shfl_xor(rsum, 32);
        l_run = l_run * alpha + rsum;
#pragma unroll
        for (int dn = 0; dn < 4; ++dn) o[dn] *= alpha;

#pragma unroll
        for (int nk = 0; nk < 4; ++nk) {
            unsigned u0, u1;
            CVTPK(u0, padd[nk][0], padd[nk][1]);
            CVTPK(u1, padd[nk][2], padd[nk][3]);
            const int cc = (nk * 16 + g * 4) ^ ((l15 & 7) << 3);
            uint2 uv; uv.x = u0; uv.y = u1;
            *reinterpret_cast<uint2*>(&Pl[w][l15 * 64 + cc]) = uv;
        }
        bf16x8 pa[2];
#pragma unroll
        for (int kk = 0; kk < 2; ++kk)
            pa[kk] = *(const bf16x8*)&Pl[w][l15 * 64 + ((kk * 32 + g * 8) ^ ((l15 & 7) << 3))];

        bf16x8 vb[4][2];
#pragma unroll
        for (int dn = 0; dn < 4; ++dn) {
            const int R = dn * 16 + l15;
            const int c0 = (g * 8) ^ ((R & 7) << 3);
            const lds_cp a0 = VB + R * 128 + c0 * 2;
            const lds_cp a1 = VB + R * 128 + (c0 ^ 32) * 2;
            DSR(vb[dn][0], a0, 0);
            DSR(vb[dn][1], a1, 0);
        }
        WAITLG;
        SCHEDB;

#pragma unroll
        for (int dn = 0; dn < 4; ++dn) {
            o[dn] = MFMA16(vb[dn][0], pa[0], o[dn]);
            o[dn] = MFMA16(vb[dn][1], pa[1], o[dn]);
        }

        __syncthreads();
        buf ^= 1;
    }

    const float rl = __builtin_amdgcn_rcpf(l_run);
    short* orow = out + ((size_t)(b * 1024) + q0 + l15) * 768 + h * 64;
#pragma unroll
    for (int dn = 0; dn < 4; ++dn) {
        unsigned u0, u1;
        const float v0 = o[dn][0] * rl, v1 = o[dn][1] * rl;
        const float v2 = o[dn][2] * rl, v3 = o[dn][3] * rl;
        CVTPK(u0, v0, v1);
        CVTPK(u1, v2, v3);
        uint2 uv; uv.x = u0; uv.y = u1;
        *reinterpret_cast<uint2*>(&orow[dn * 16 + g * 4]) = uv;
    }
}

// ---------------------------------------------------------------------------
// Launch
// ---------------------------------------------------------------------------
extern "C" void kernel_launch(void* const* d_in, const int* in_sizes, int n_in,
                              void* d_out, int out_size, void* d_ws, size_t ws_size,
                              hipStream_t stream) {
    const float* x      = (const float*)d_in[0];
    const float* ln1_g  = (const float*)d_in[1];
    const float* ln1_b  = (const float*)d_in[2];
    const float* qkv_w  = (const float*)d_in[3];
    const float* qkv_b  = (const float*)d_in[4];
    const float* proj_w = (const float*)d_in[5];
    const float* proj_b = (const float*)d_in[6];
    const float* ln2_g  = (const float*)d_in[7];
    const float* ln2_b  = (const float*)d_in[8];
    const float* fc1_w  = (const float*)d_in[9];
    const float* fc1_b  = (const float*)d_in[10];
    const float* fc2_w  = (const float*)d_in[11];
    const float* fc2_b  = (const float*)d_in[12];
    float* outp = (float*)d_out;

    char* ws = (char*)d_ws;
    size_t off = 0;
    auto alloc = [&](size_t bytes) {
        char* p = ws + off;
        off = (off + bytes + 255) & ~(size_t)255;
        return p;
    };
    short* wt_qkv  = (short*)alloc(2304ull * 768 * 2);
    short* wt_proj = (short*)alloc(768ull * 768 * 2);
    short* wt_fc1  = (short*)alloc(3072ull * 768 * 2);
    short* wt_fc2  = (short*)alloc(768ull * 3072 * 2);
    short* hbuf    = (short*)alloc(8192ull * 768 * 2);
    short* Qb      = (short*)alloc(8192ull * 768 * 2);   // [B,NH,S,HD]
    short* Kbuf    = (short*)alloc(8192ull * 768 * 2);   // [B,NH,S,HD]
    short* Vtb     = (short*)alloc(8192ull * 768 * 2);   // [B,NH,HD,S]
    short* attnb   = (short*)alloc(8192ull * 768 * 2);   // [B,S,H]
    float* x2      = (float*)alloc(8192ull * 768 * 4);   // fp32 residual stream
    short* mfc     = Qb;  // alias: fc1 output [8192,3072] over dead Q/K/Vt/attn
    (void)ws_size; (void)in_sizes; (void)n_in; (void)out_size;

    // weight prep
    transpose_w<<<dim3(2304 / 32, 768 / 32), 256, 0, stream>>>(qkv_w, wt_qkv, 768, 2304);
    transpose_w<<<dim3(768 / 32, 768 / 32), 256, 0, stream>>>(proj_w, wt_proj, 768, 768);
    transpose_w<<<dim3(3072 / 32, 768 / 32), 256, 0, stream>>>(fc1_w, wt_fc1, 768, 3072);
    transpose_w<<<dim3(768 / 32, 3072 / 32), 256, 0, stream>>>(fc2_w, wt_fc2, 3072, 768);

    // attention sublayer
    ln_k<<<8192, 192, 0, stream>>>(x, ln1_g, ln1_b, hbuf);
    gemm3p<MODE_QKV><<<dim3(64, 18), 256, 0, stream>>>(
        hbuf, wt_qkv, qkv_b, nullptr, nullptr, nullptr, Qb, Kbuf, Vtb, 8192, 2304, 768);
    attn_k<<<1536, 256, 0, stream>>>(Qb, Kbuf, Vtb, attnb);
    gemm3p<MODE_F32RES><<<dim3(64, 6), 256, 0, stream>>>(
        attnb, wt_proj, proj_b, x, x2, nullptr, nullptr, nullptr, nullptr, 8192, 768, 768);

    // MLP sublayer
    ln_k<<<8192, 192, 0, stream>>>(x2, ln2_g, ln2_b, hbuf);
    gemm3p<MODE_GELU><<<dim3(64, 24), 256, 0, stream>>>(
        hbuf, wt_fc1, fc1_b, nullptr, nullptr, mfc, nullptr, nullptr, nullptr, 8192, 3072, 768);
    gemm3p<MODE_F32RES><<<dim3(64, 6), 256, 0, stream>>>(
        mfc, wt_fc2, fc2_b, x2, outp, nullptr, nullptr, nullptr, nullptr, 8192, 768, 3072);
}

// Round 13
// 273.327 us; speedup vs baseline: 1.1982x; 1.0156x over previous
//
#include <hip/hip_runtime.h>
#include <hip/hip_bf16.h>

// ---------------------------------------------------------------------------
// Transformer block, B=8 S=1024 H=768 NH=12 HD=64 I=3072.  fp32 in/out,
// bf16 MFMA internals.
// Round 13: gemm3p LDS 48KB->32KB (2 buffers) => 5 blocks/CU (was 3).
// Occupancy was the binding constraint (LDS/MFMA pipes each only ~25-30%
// loaded; all latency exposed at 3 blocks/CU).  Counted-vmcnt schedule kept;
// stage(t+2) re-placed AFTER the reads-done barrier into the just-read
// buffer (WAR-safe), landing verified by WAITV4 at t+2's loop top.
// Epilogue/attn/LN unchanged from round 12.
// ---------------------------------------------------------------------------

typedef __attribute__((ext_vector_type(8))) short bf16x8;
typedef __attribute__((ext_vector_type(4))) float f32x4;
typedef const __attribute__((address_space(3))) char* lds_cp;

#define MFMA16(a, b, c) __builtin_amdgcn_mfma_f32_16x16x32_bf16((a), (b), (c), 0, 0, 0)

// inline-asm LDS read: invisible to compiler alias analysis (no auto-vmcnt).
#define DSR(dst, addr, off) \
    asm volatile("ds_read_b128 %0, %1 offset:" #off : "=v"(dst) : "v"(addr))
#define WAITV4 asm volatile("s_waitcnt vmcnt(4)" ::: "memory")
#define WAITV0 asm volatile("s_waitcnt vmcnt(0)" ::: "memory")
#define WAITLG asm volatile("s_waitcnt lgkmcnt(0)" ::: "memory")
#define SCHEDB __builtin_amdgcn_sched_barrier(0)
// packed f32x2 -> bf16x2 (RNE), single instruction; low short = first src
#define CVTPK(d, lo, hi) \
    asm("v_cvt_pk_bf16_f32 %0, %1, %2" : "=v"(d) : "v"(lo), "v"(hi))

__device__ inline short f2bf(float x) {
    __hip_bfloat16 h = __float2bfloat16(x);
    return *reinterpret_cast<short*>(&h);
}

__device__ inline void gload_lds16(const void* g, void* lds) {
    __builtin_amdgcn_global_load_lds(
        (const __attribute__((address_space(1))) unsigned int*)g,
        (__attribute__((address_space(3))) unsigned int*)lds,
        16, 0, 0);
}

// ---------------------------------------------------------------------------
// Weight prep: W fp32 [K,N] -> Wt bf16 [N,K]   (tiled transpose + cast)
// ---------------------------------------------------------------------------
__global__ __launch_bounds__(256) void transpose_w(
    const float* __restrict__ W, short* __restrict__ Wt, int K, int N) {
    __shared__ float tile[32][33];
    const int tx = threadIdx.x & 31, ty = threadIdx.x >> 5;  // ty 0..7
    const int n0 = blockIdx.x * 32, k0 = blockIdx.y * 32;
#pragma unroll
    for (int i = 0; i < 4; ++i)
        tile[ty + i * 8][tx] = W[(size_t)(k0 + ty + i * 8) * N + n0 + tx];
    __syncthreads();
#pragma unroll
    for (int i = 0; i < 4; ++i)
        Wt[(size_t)(n0 + ty + i * 8) * K + k0 + tx] = f2bf(tile[tx][ty + i * 8]);
}

// ---------------------------------------------------------------------------
// LayerNorm: fp32 [M,768] -> bf16 [M,768].  192 threads/row, float4 loads,
// packed uint2 stores.
// ---------------------------------------------------------------------------
__global__ __launch_bounds__(192) void ln_k(
    const float* __restrict__ x, const float* __restrict__ g,
    const float* __restrict__ b, short* __restrict__ out) {
    const int row = blockIdx.x;
    const int tid = threadIdx.x;
    const float4 v = *reinterpret_cast<const float4*>(&x[(size_t)row * 768 + tid * 4]);
    float s = v.x + v.y + v.z + v.w;
    float sq = v.x * v.x + v.y * v.y + v.z * v.z + v.w * v.w;
#pragma unroll
    for (int off = 32; off >= 1; off >>= 1) {
        s += __shfl_xor(s, off);
        sq += __shfl_xor(sq, off);
    }
    __shared__ float ss[3], ssq[3];
    const int wid = tid >> 6;
    if ((tid & 63) == 0) { ss[wid] = s; ssq[wid] = sq; }
    __syncthreads();
    s = ss[0] + ss[1] + ss[2];
    sq = ssq[0] + ssq[1] + ssq[2];
    const float mean = s * (1.0f / 768.0f);
    const float var = sq * (1.0f / 768.0f) - mean * mean;  // biased
    const float rstd = rsqrtf(var + 1e-5f);
    const float4 gg = *reinterpret_cast<const float4*>(&g[tid * 4]);
    const float4 bb = *reinterpret_cast<const float4*>(&b[tid * 4]);
    const float r0 = (v.x - mean) * rstd * gg.x + bb.x;
    const float r1 = (v.y - mean) * rstd * gg.y + bb.y;
    const float r2 = (v.z - mean) * rstd * gg.z + bb.z;
    const float r3 = (v.w - mean) * rstd * gg.w + bb.w;
    unsigned u0, u1;
    CVTPK(u0, r0, r1);
    CVTPK(u1, r2, r3);
    uint2 uv; uv.x = u0; uv.y = u1;
    *reinterpret_cast<uint2*>(&out[(size_t)row * 768 + tid * 4]) = uv;
}

enum { MODE_BF16 = 0, MODE_QKV = 1, MODE_F32RES = 2, MODE_GELU = 3 };

// ---------------------------------------------------------------------------
// Packed 4-wide epilogue: thread owns C[mrow][nbase..nbase+3].
// ---------------------------------------------------------------------------
template <int MODE>
__device__ inline void epi_store4(
    const float* v4, int mrow, int nbase, int N,
    const float* __restrict__ resid, float* __restrict__ outf,
    short* __restrict__ outh, short* __restrict__ Qo,
    short* __restrict__ Ko, short* __restrict__ Vto) {
    if constexpr (MODE == MODE_BF16) {
        unsigned u0, u1;
        CVTPK(u0, v4[0], v4[1]);
        CVTPK(u1, v4[2], v4[3]);
        uint2 uv; uv.x = u0; uv.y = u1;
        *reinterpret_cast<uint2*>(&outh[(size_t)mrow * N + nbase]) = uv;
    } else if constexpr (MODE == MODE_GELU) {
        float gl[4];
#pragma unroll
        for (int r = 0; r < 4; ++r) {
            const float vv = v4[r];
            const float u = 0.7978845608028654f * (vv + 0.044715f * vv * vv * vv);
            gl[r] = vv / (1.0f + __expf(-2.0f * u));
        }
        unsigned u0, u1;
        CVTPK(u0, gl[0], gl[1]);
        CVTPK(u1, gl[2], gl[3]);
        uint2 uv; uv.x = u0; uv.y = u1;
        *reinterpret_cast<uint2*>(&outh[(size_t)mrow * N + nbase]) = uv;
    } else if constexpr (MODE == MODE_F32RES) {
        const float4 rs = *reinterpret_cast<const float4*>(&resid[(size_t)mrow * N + nbase]);
        float4 o4;
        o4.x = v4[0] + rs.x;
        o4.y = v4[1] + rs.y;
        o4.z = v4[2] + rs.z;
        o4.w = v4[3] + rs.w;
        *reinterpret_cast<float4*>(&outf[(size_t)mrow * N + nbase]) = o4;
    } else {  // MODE_QKV
        const int bb = mrow >> 10, s = mrow & 1023;
        if (nbase < 768) {
            const int hh = nbase >> 6, d = nbase & 63;
            unsigned u0, u1;
            CVTPK(u0, v4[0] * 0.125f, v4[1] * 0.125f);
            CVTPK(u1, v4[2] * 0.125f, v4[3] * 0.125f);
            uint2 uv; uv.x = u0; uv.y = u1;
            *reinterpret_cast<uint2*>(
                &Qo[(((size_t)(bb * 12 + hh)) * 1024 + s) * 64 + d]) = uv;
        } else if (nbase < 1536) {
            const int c2 = nbase - 768;
            const int hh = c2 >> 6, d = c2 & 63;
            unsigned u0, u1;
            CVTPK(u0, v4[0], v4[1]);
            CVTPK(u1, v4[2], v4[3]);
            uint2 uv; uv.x = u0; uv.y = u1;
            *reinterpret_cast<uint2*>(
                &Ko[(((size_t)(bb * 12 + hh)) * 1024 + s) * 64 + d]) = uv;
        } else {
            const int c2 = nbase - 1536;
            const int hh = c2 >> 6, d = c2 & 63;
#pragma unroll
            for (int r = 0; r < 4; ++r)
                Vto[(((size_t)(bb * 12 + hh)) * 64 + d + r) * 1024 + s] = f2bf(v4[r]);
        }
    }
}

// ---------------------------------------------------------------------------
// gemm3p: 128x128 tile, BK=32, TWO LDS buffers (32KB -> 5 blocks/CU).
// Iter t: WAITV4 (V0 on last 2) | barrier | 8 asm ds_reads buf t&1 |
// lgkm | 16 MFMA (swapped operands) | barrier | stage(buf t&1, t+2).
// Stage flies across the next full iteration; no vmcnt(0) drain in loop.
// LDS placement: logical (row R, 16B-unit cu) at physical unit
// R*4 + (cu ^ ((R>>1)&3))  (2-way, conflict-free -- verified 0).
// ---------------------------------------------------------------------------
template <int MODE>
__global__ __launch_bounds__(256) void gemm3p(
    const short* __restrict__ A, const short* __restrict__ Wt,
    const float* __restrict__ bias, const float* __restrict__ resid,
    float* __restrict__ outf, short* __restrict__ outh,
    short* __restrict__ Qo, short* __restrict__ Ko, short* __restrict__ Vto,
    int M, int N, int K) {
    __shared__ __attribute__((aligned(128))) short Al[2][4096];
    __shared__ __attribute__((aligned(128))) short Bl[2][4096];
    const int tid = threadIdx.x;
    const int lane = tid & 63;
    const int w = tid >> 6;
    const int wm = w >> 1, wn = w & 1;
    const int m0 = blockIdx.x * 128, n0 = blockIdx.y * 128;

    f32x4 acc[4][4] = {};

    // staging: thread tid fills physical unit tid (linear dest); logical
    // source unit cu = (tid&3) ^ ((tid>>3)&3).
    const int srow = tid >> 2;
    const int scol = (((tid & 3) ^ ((tid >> 3) & 3)) * 8);
    const short* Abase = A + (size_t)(m0 + srow) * K + scol;
    const short* Bbase = Wt + (size_t)(n0 + srow) * K + scol;
    const size_t K64 = (size_t)K * 64;
    short* const AlF = &Al[0][0];
    short* const BlF = &Bl[0][0];

    auto stageT = [&](int boS, int k0s) {
        gload_lds16(Abase + k0s,       AlF + boS + w * 512);
        gload_lds16(Abase + K64 + k0s, AlF + boS + 2048 + w * 512);
        gload_lds16(Bbase + k0s,       BlF + boS + w * 512);
        gload_lds16(Bbase + K64 + k0s, BlF + boS + 2048 + w * 512);
    };

    // fragment read: logical (R = l15 + 16*mi, cu = g) at physical byte
    // R*64 + (g ^ ((R>>1)&3))*16; 16*mi preserves the swizzle bits.
    const int l15 = lane & 15, g = lane >> 4;
    const int lcolswz = (g ^ ((l15 >> 1) & 3)) << 4;
    const int aoff = wm * 4096 + l15 * 64 + lcolswz;
    const int boff = wn * 4096 + l15 * 64 + lcolswz;
    const lds_cp AlB = (lds_cp)AlF;
    const lds_cp BlB = (lds_cp)BlF;

    const int NT = K >> 5;  // >= 2 always here (K = 768 or 3072)

    // prologue: tiles 0,1 -> bufs 0,1 (8 loads outstanding)
    stageT(0, 0);
    stageT(4096, 32);

    for (int t = 0; t < NT; ++t) {
        // landed-wait for tile t: 8 outstanding in steady state -> vmcnt(4);
        // last two iterations have no further prefetch -> drain to 0.
        if (t < NT - 2) { WAITV4; } else { WAITV0; }
        SCHEDB;
        __builtin_amdgcn_s_barrier();   // all waves' tile-t stages landed

        const int bo = (t & 1) * 8192;  // byte offset of buf t&1
        const lds_cp Ab = AlB + (bo + aoff);
        const lds_cp Bb = BlB + (bo + boff);
        bf16x8 av0, av1, av2, av3, bv0, bv1, bv2, bv3;
        DSR(av0, Ab, 0);
        DSR(av1, Ab, 1024);
        DSR(av2, Ab, 2048);
        DSR(av3, Ab, 3072);
        DSR(bv0, Bb, 0);
        DSR(bv1, Bb, 1024);
        DSR(bv2, Bb, 2048);
        DSR(bv3, Bb, 3072);
        WAITLG;
        SCHEDB;

        __builtin_amdgcn_s_setprio(1);
        {
            bf16x8 av[4] = {av0, av1, av2, av3};
            bf16x8 bv[4] = {bv0, bv1, bv2, bv3};
#pragma unroll
            for (int mi = 0; mi < 4; ++mi)
#pragma unroll
                for (int ni = 0; ni < 4; ++ni)
                    acc[mi][ni] = MFMA16(bv[ni], av[mi], acc[mi][ni]);  // swapped
        }
        __builtin_amdgcn_s_setprio(0);
        __builtin_amdgcn_s_barrier();   // all reads of buf t&1 done
        SCHEDB;

        if (t + 2 < NT) stageT((t & 1) * 4096, (t + 2) << 5);  // WAR-safe
    }
    // nothing outstanding: last stage was waited by WAITV0 at t = NT-1

    // Epilogue: swapped D layout -> thread owns C[mrow][nbase..nbase+3].
#pragma unroll
    for (int ni = 0; ni < 4; ++ni) {
        const int nbase = n0 + wn * 64 + ni * 16 + g * 4;
        const float4 b4 = *reinterpret_cast<const float4*>(&bias[nbase]);
#pragma unroll
        for (int mi = 0; mi < 4; ++mi) {
            const int mrow = m0 + wm * 64 + mi * 16 + l15;
            float v4[4] = {acc[mi][ni][0] + b4.x, acc[mi][ni][1] + b4.y,
                           acc[mi][ni][2] + b4.z, acc[mi][ni][3] + b4.w};
            epi_store4<MODE>(v4, mrow, nbase, N, resid, outf, outh, Qo, Ko, Vto);
        }
    }
}

// ---------------------------------------------------------------------------
// Flash attention, swapped-operand softmax (unchanged from round 8).
// ---------------------------------------------------------------------------
__global__ __launch_bounds__(256) void attn_k(
    const short* __restrict__ Q, const short* __restrict__ Kg,
    const short* __restrict__ Vtg, short* __restrict__ out) {
    __shared__ __attribute__((aligned(128))) short Kl[2][64 * 64];
    __shared__ __attribute__((aligned(128))) short Vl[2][64 * 64];
    __shared__ __attribute__((aligned(128))) short Pl[4][16 * 64];
    const int tid = threadIdx.x, lane = tid & 63, w = tid >> 6;
    const int swz = (blockIdx.x & 7) * 192 + (blockIdx.x >> 3);
    const int qt = swz & 15, bh = swz >> 4;
    const int b = bh / 12, h = bh % 12;
    const int q0 = qt * 64 + w * 16;
    const int l15 = lane & 15, g = lane >> 4;

    bf16x8 aq[2];
    const short* Qb = Q + ((size_t)bh * 1024 + q0) * 64;
#pragma unroll
    for (int kk = 0; kk < 2; ++kk)
        aq[kk] = *(const bf16x8*)&Qb[(size_t)l15 * 64 + kk * 32 + g * 8];

    float m_run = -1e30f, l_run = 0.f;
    f32x4 o[4] = {};

    const short* Kb = Kg + (size_t)bh * 1024 * 64;
    const short* Vb = Vtg + (size_t)bh * 64 * 1024;

    const int srr = tid >> 3;
    const int spp = (tid & 7) * 8;
    const int ssc = spp ^ ((srr & 7) << 3);
    auto stage = [&](int buf, int kv0) {
        gload_lds16(Kb + (size_t)(kv0 + srr) * 64 + ssc,        &Kl[buf][w * 512]);
        gload_lds16(Kb + (size_t)(kv0 + 32 + srr) * 64 + ssc,   &Kl[buf][2048 + w * 512]);
        gload_lds16(Vb + (size_t)srr * 1024 + kv0 + ssc,        &Vl[buf][w * 512]);
        gload_lds16(Vb + (size_t)(srr + 32) * 1024 + kv0 + ssc, &Vl[buf][2048 + w * 512]);
    };

    stage(0, 0);
    __syncthreads();

    int buf = 0;
    for (int t = 0; t < 16; ++t) {
        const lds_cp KB = (lds_cp)&Kl[buf][0];
        const lds_cp VB = (lds_cp)&Vl[buf][0];

        bf16x8 kb[4][2];
#pragma unroll
        for (int nk = 0; nk < 4; ++nk) {
            const int R = nk * 16 + l15;
            const int c0 = (g * 8) ^ ((R & 7) << 3);
            const lds_cp a0 = KB + R * 128 + c0 * 2;
            const lds_cp a1 = KB + R * 128 + (c0 ^ 32) * 2;
            DSR(kb[nk][0], a0, 0);
            DSR(kb[nk][1], a1, 0);
        }

        if (t < 15) stage(buf ^ 1, (t + 1) * 64);

        WAITLG;
        SCHEDB;

        f32x4 sc4[4];
#pragma unroll
        for (int nk = 0; nk < 4; ++nk) {
            f32x4 z = {};
            z = MFMA16(kb[nk][0], aq[0], z);
            z = MFMA16(kb[nk][1], aq[1], z);
            sc4[nk] = z;
        }

        float ml = sc4[0][0];
#pragma unroll
        for (int nk = 0; nk < 4; ++nk)
#pragma unroll
            for (int r = 0; r < 4; ++r) ml = fmaxf(ml, sc4[nk][r]);
        ml = fmaxf(ml, __shfl_xor(ml, 16));
        ml = fmaxf(ml, __shfl_xor(ml, 32));
        const float mn = fmaxf(m_run, ml);
        const float alpha = __expf(m_run - mn);
        m_run = mn;
        float padd[4][4];
        float rsum = 0.f;
#pragma unroll
        for (int nk = 0; nk < 4; ++nk)
#pragma unroll
            for (int r = 0; r < 4; ++r) {
                padd[nk][r] = __expf(sc4[nk][r] - mn);
                rsum += padd[nk][r];
            }
        rsum += __shfl_xor(rsum, 16);
        rsum += __shfl_xor(rsum, 32);
        l_run = l_run * alpha + rsum;
#pragma unroll
        for (int dn = 0; dn < 4; ++dn) o[dn] *= alpha;

#pragma unroll
        for (int nk = 0; nk < 4; ++nk) {
            unsigned u0, u1;
            CVTPK(u0, padd[nk][0], padd[nk][1]);
            CVTPK(u1, padd[nk][2], padd[nk][3]);
            const int cc = (nk * 16 + g * 4) ^ ((l15 & 7) << 3);
            uint2 uv; uv.x = u0; uv.y = u1;
            *reinterpret_cast<uint2*>(&Pl[w][l15 * 64 + cc]) = uv;
        }
        bf16x8 pa[2];
#pragma unroll
        for (int kk = 0; kk < 2; ++kk)
            pa[kk] = *(const bf16x8*)&Pl[w][l15 * 64 + ((kk * 32 + g * 8) ^ ((l15 & 7) << 3))];

        bf16x8 vb[4][2];
#pragma unroll
        for (int dn = 0; dn < 4; ++dn) {
            const int R = dn * 16 + l15;
            const int c0 = (g * 8) ^ ((R & 7) << 3);
            const lds_cp a0 = VB + R * 128 + c0 * 2;
            const lds_cp a1 = VB + R * 128 + (c0 ^ 32) * 2;
            DSR(vb[dn][0], a0, 0);
            DSR(vb[dn][1], a1, 0);
        }
        WAITLG;
        SCHEDB;

#pragma unroll
        for (int dn = 0; dn < 4; ++dn) {
            o[dn] = MFMA16(vb[dn][0], pa[0], o[dn]);
            o[dn] = MFMA16(vb[dn][1], pa[1], o[dn]);
        }

        __syncthreads();
        buf ^= 1;
    }

    const float rl = __builtin_amdgcn_rcpf(l_run);
    short* orow = out + ((size_t)(b * 1024) + q0 + l15) * 768 + h * 64;
#pragma unroll
    for (int dn = 0; dn < 4; ++dn) {
        unsigned u0, u1;
        const float v0 = o[dn][0] * rl, v1 = o[dn][1] * rl;
        const float v2 = o[dn][2] * rl, v3 = o[dn][3] * rl;
        CVTPK(u0, v0, v1);
        CVTPK(u1, v2, v3);
        uint2 uv; uv.x = u0; uv.y = u1;
        *reinterpret_cast<uint2*>(&orow[dn * 16 + g * 4]) = uv;
    }
}

// ---------------------------------------------------------------------------
// Launch
// ---------------------------------------------------------------------------
extern "C" void kernel_launch(void* const* d_in, const int* in_sizes, int n_in,
                              void* d_out, int out_size, void* d_ws, size_t ws_size,
                              hipStream_t stream) {
    const float* x      = (const float*)d_in[0];
    const float* ln1_g  = (const float*)d_in[1];
    const float* ln1_b  = (const float*)d_in[2];
    const float* qkv_w  = (const float*)d_in[3];
    const float* qkv_b  = (const float*)d_in[4];
    const float* proj_w = (const float*)d_in[5];
    const float* proj_b = (const float*)d_in[6];
    const float* ln2_g  = (const float*)d_in[7];
    const float* ln2_b  = (const float*)d_in[8];
    const float* fc1_w  = (const float*)d_in[9];
    const float* fc1_b  = (const float*)d_in[10];
    const float* fc2_w  = (const float*)d_in[11];
    const float* fc2_b  = (const float*)d_in[12];
    float* outp = (float*)d_out;

    char* ws = (char*)d_ws;
    size_t off = 0;
    auto alloc = [&](size_t bytes) {
        char* p = ws + off;
        off = (off + bytes + 255) & ~(size_t)255;
        return p;
    };
    short* wt_qkv  = (short*)alloc(2304ull * 768 * 2);
    short* wt_proj = (short*)alloc(768ull * 768 * 2);
    short* wt_fc1  = (short*)alloc(3072ull * 768 * 2);
    short* wt_fc2  = (short*)alloc(768ull * 3072 * 2);
    short* hbuf    = (short*)alloc(8192ull * 768 * 2);
    short* Qb      = (short*)alloc(8192ull * 768 * 2);   // [B,NH,S,HD]
    short* Kbuf    = (short*)alloc(8192ull * 768 * 2);   // [B,NH,S,HD]
    short* Vtb     = (short*)alloc(8192ull * 768 * 2);   // [B,NH,HD,S]
    short* attnb   = (short*)alloc(8192ull * 768 * 2);   // [B,S,H]
    float* x2      = (float*)alloc(8192ull * 768 * 4);   // fp32 residual stream
    short* mfc     = Qb;  // alias: fc1 output [8192,3072] over dead Q/K/Vt/attn
    (void)ws_size; (void)in_sizes; (void)n_in; (void)out_size;

    // weight prep
    transpose_w<<<dim3(2304 / 32, 768 / 32), 256, 0, stream>>>(qkv_w, wt_qkv, 768, 2304);
    transpose_w<<<dim3(768 / 32, 768 / 32), 256, 0, stream>>>(proj_w, wt_proj, 768, 768);
    transpose_w<<<dim3(3072 / 32, 768 / 32), 256, 0, stream>>>(fc1_w, wt_fc1, 768, 3072);
    transpose_w<<<dim3(768 / 32, 3072 / 32), 256, 0, stream>>>(fc2_w, wt_fc2, 3072, 768);

    // attention sublayer
    ln_k<<<8192, 192, 0, stream>>>(x, ln1_g, ln1_b, hbuf);
    gemm3p<MODE_QKV><<<dim3(64, 18), 256, 0, stream>>>(
        hbuf, wt_qkv, qkv_b, nullptr, nullptr, nullptr, Qb, Kbuf, Vtb, 8192, 2304, 768);
    attn_k<<<1536, 256, 0, stream>>>(Qb, Kbuf, Vtb, attnb);
    gemm3p<MODE_F32RES><<<dim3(64, 6), 256, 0, stream>>>(
        attnb, wt_proj, proj_b, x, x2, nullptr, nullptr, nullptr, nullptr, 8192, 768, 768);

    // MLP sublayer
    ln_k<<<8192, 192, 0, stream>>>(x2, ln2_g, ln2_b, hbuf);
    gemm3p<MODE_GELU><<<dim3(64, 24), 256, 0, stream>>>(
        hbuf, wt_fc1, fc1_b, nullptr, nullptr, mfc, nullptr, nullptr, nullptr, 8192, 3072, 768);
    gemm3p<MODE_F32RES><<<dim3(64, 6), 256, 0, stream>>>(
        mfc, wt_fc2, fc2_b, x2, outp, nullptr, nullptr, nullptr, nullptr, 8192, 768, 3072);
}

// Round 14
// 271.941 us; speedup vs baseline: 1.2043x; 1.0051x over previous
//
#include <hip/hip_runtime.h>
#include <hip/hip_bf16.h>

// ---------------------------------------------------------------------------
// Transformer block, B=8 S=1024 H=768 NH=12 HD=64 I=3072.  fp32 in/out,
// bf16 MFMA internals.
// Round 14: gemm3p gets fine-grained lgkm-counted MFMA sub-clusters
// (4x4 MFMA gated by lgkmcnt(3/2/1/0) -- reconstructs the compiler-style
// ds_read<->MFMA overlap that the asm reads destroyed) + 4 LDS buffers,
// depth-3 prefetch, ONE barrier + counted vmcnt(8) per K-tile.
// transpose_w x4 merged into one kernel.  attn/LN/epilogues unchanged.
// ---------------------------------------------------------------------------

typedef __attribute__((ext_vector_type(8))) short bf16x8;
typedef __attribute__((ext_vector_type(4))) float f32x4;
typedef const __attribute__((address_space(3))) char* lds_cp;

#define MFMA16(a, b, c) __builtin_amdgcn_mfma_f32_16x16x32_bf16((a), (b), (c), 0, 0, 0)

// inline-asm LDS read: invisible to compiler alias analysis (no auto-vmcnt).
#define DSR(dst, addr, off) \
    asm volatile("ds_read_b128 %0, %1 offset:" #off : "=v"(dst) : "v"(addr))
#define WAITV8 asm volatile("s_waitcnt vmcnt(8)" ::: "memory")
#define WAITV0 asm volatile("s_waitcnt vmcnt(0)" ::: "memory")
#define WAITLG3 asm volatile("s_waitcnt lgkmcnt(3)" ::: "memory")
#define WAITLG2 asm volatile("s_waitcnt lgkmcnt(2)" ::: "memory")
#define WAITLG1 asm volatile("s_waitcnt lgkmcnt(1)" ::: "memory")
#define WAITLG asm volatile("s_waitcnt lgkmcnt(0)" ::: "memory")
#define SCHEDB __builtin_amdgcn_sched_barrier(0)
// packed f32x2 -> bf16x2 (RNE), single instruction; low short = first src
#define CVTPK(d, lo, hi) \
    asm("v_cvt_pk_bf16_f32 %0, %1, %2" : "=v"(d) : "v"(lo), "v"(hi))

__device__ inline short f2bf(float x) {
    __hip_bfloat16 h = __float2bfloat16(x);
    return *reinterpret_cast<short*>(&h);
}

__device__ inline void gload_lds16(const void* g, void* lds) {
    __builtin_amdgcn_global_load_lds(
        (const __attribute__((address_space(1))) unsigned int*)g,
        (__attribute__((address_space(3))) unsigned int*)lds,
        16, 0, 0);
}

// ---------------------------------------------------------------------------
// Merged weight prep: all four W fp32 [K,N] -> Wt bf16 [N,K] in one launch.
// Block counts: qkv 72x24=1728, proj 24x24=576, fc1 96x24=2304, fc2 24x96=2304.
// ---------------------------------------------------------------------------
__global__ __launch_bounds__(256) void transpose_all(
    const float* __restrict__ qkv_w, const float* __restrict__ proj_w,
    const float* __restrict__ fc1_w, const float* __restrict__ fc2_w,
    short* __restrict__ wt_qkv, short* __restrict__ wt_proj,
    short* __restrict__ wt_fc1, short* __restrict__ wt_fc2) {
    int b = blockIdx.x;
    const float* W;
    short* Wt;
    int K, N, nb;
    if (b < 1728) {
        W = qkv_w; Wt = wt_qkv; K = 768; N = 2304; nb = 72;
    } else if (b < 2304) {
        b -= 1728; W = proj_w; Wt = wt_proj; K = 768; N = 768; nb = 24;
    } else if (b < 4608) {
        b -= 2304; W = fc1_w; Wt = wt_fc1; K = 768; N = 3072; nb = 96;
    } else {
        b -= 4608; W = fc2_w; Wt = wt_fc2; K = 3072; N = 768; nb = 24;
    }
    __shared__ float tile[32][33];
    const int tx = threadIdx.x & 31, ty = threadIdx.x >> 5;  // ty 0..7
    const int n0 = (b % nb) * 32, k0 = (b / nb) * 32;
#pragma unroll
    for (int i = 0; i < 4; ++i)
        tile[ty + i * 8][tx] = W[(size_t)(k0 + ty + i * 8) * N + n0 + tx];
    __syncthreads();
#pragma unroll
    for (int i = 0; i < 4; ++i)
        Wt[(size_t)(n0 + ty + i * 8) * K + k0 + tx] = f2bf(tile[tx][ty + i * 8]);
}

// ---------------------------------------------------------------------------
// LayerNorm: fp32 [M,768] -> bf16 [M,768].  192 threads/row, float4 loads,
// packed uint2 stores.
// ---------------------------------------------------------------------------
__global__ __launch_bounds__(192) void ln_k(
    const float* __restrict__ x, const float* __restrict__ g,
    const float* __restrict__ b, short* __restrict__ out) {
    const int row = blockIdx.x;
    const int tid = threadIdx.x;
    const float4 v = *reinterpret_cast<const float4*>(&x[(size_t)row * 768 + tid * 4]);
    float s = v.x + v.y + v.z + v.w;
    float sq = v.x * v.x + v.y * v.y + v.z * v.z + v.w * v.w;
#pragma unroll
    for (int off = 32; off >= 1; off >>= 1) {
        s += __shfl_xor(s, off);
        sq += __shfl_xor(sq, off);
    }
    __shared__ float ss[3], ssq[3];
    const int wid = tid >> 6;
    if ((tid & 63) == 0) { ss[wid] = s; ssq[wid] = sq; }
    __syncthreads();
    s = ss[0] + ss[1] + ss[2];
    sq = ssq[0] + ssq[1] + ssq[2];
    const float mean = s * (1.0f / 768.0f);
    const float var = sq * (1.0f / 768.0f) - mean * mean;  // biased
    const float rstd = rsqrtf(var + 1e-5f);
    const float4 gg = *reinterpret_cast<const float4*>(&g[tid * 4]);
    const float4 bb = *reinterpret_cast<const float4*>(&b[tid * 4]);
    const float r0 = (v.x - mean) * rstd * gg.x + bb.x;
    const float r1 = (v.y - mean) * rstd * gg.y + bb.y;
    const float r2 = (v.z - mean) * rstd * gg.z + bb.z;
    const float r3 = (v.w - mean) * rstd * gg.w + bb.w;
    unsigned u0, u1;
    CVTPK(u0, r0, r1);
    CVTPK(u1, r2, r3);
    uint2 uv; uv.x = u0; uv.y = u1;
    *reinterpret_cast<uint2*>(&out[(size_t)row * 768 + tid * 4]) = uv;
}

enum { MODE_BF16 = 0, MODE_QKV = 1, MODE_F32RES = 2, MODE_GELU = 3 };

// ---------------------------------------------------------------------------
// Packed 4-wide epilogue: thread owns C[mrow][nbase..nbase+3].
// ---------------------------------------------------------------------------
template <int MODE>
__device__ inline void epi_store4(
    const float* v4, int mrow, int nbase, int N,
    const float* __restrict__ resid, float* __restrict__ outf,
    short* __restrict__ outh, short* __restrict__ Qo,
    short* __restrict__ Ko, short* __restrict__ Vto) {
    if constexpr (MODE == MODE_BF16) {
        unsigned u0, u1;
        CVTPK(u0, v4[0], v4[1]);
        CVTPK(u1, v4[2], v4[3]);
        uint2 uv; uv.x = u0; uv.y = u1;
        *reinterpret_cast<uint2*>(&outh[(size_t)mrow * N + nbase]) = uv;
    } else if constexpr (MODE == MODE_GELU) {
        float gl[4];
#pragma unroll
        for (int r = 0; r < 4; ++r) {
            const float vv = v4[r];
            const float u = 0.7978845608028654f * (vv + 0.044715f * vv * vv * vv);
            gl[r] = vv / (1.0f + __expf(-2.0f * u));
        }
        unsigned u0, u1;
        CVTPK(u0, gl[0], gl[1]);
        CVTPK(u1, gl[2], gl[3]);
        uint2 uv; uv.x = u0; uv.y = u1;
        *reinterpret_cast<uint2*>(&outh[(size_t)mrow * N + nbase]) = uv;
    } else if constexpr (MODE == MODE_F32RES) {
        const float4 rs = *reinterpret_cast<const float4*>(&resid[(size_t)mrow * N + nbase]);
        float4 o4;
        o4.x = v4[0] + rs.x;
        o4.y = v4[1] + rs.y;
        o4.z = v4[2] + rs.z;
        o4.w = v4[3] + rs.w;
        *reinterpret_cast<float4*>(&outf[(size_t)mrow * N + nbase]) = o4;
    } else {  // MODE_QKV
        const int bb = mrow >> 10, s = mrow & 1023;
        if (nbase < 768) {
            const int hh = nbase >> 6, d = nbase & 63;
            unsigned u0, u1;
            CVTPK(u0, v4[0] * 0.125f, v4[1] * 0.125f);
            CVTPK(u1, v4[2] * 0.125f, v4[3] * 0.125f);
            uint2 uv; uv.x = u0; uv.y = u1;
            *reinterpret_cast<uint2*>(
                &Qo[(((size_t)(bb * 12 + hh)) * 1024 + s) * 64 + d]) = uv;
        } else if (nbase < 1536) {
            const int c2 = nbase - 768;
            const int hh = c2 >> 6, d = c2 & 63;
            unsigned u0, u1;
            CVTPK(u0, v4[0], v4[1]);
            CVTPK(u1, v4[2], v4[3]);
            uint2 uv; uv.x = u0; uv.y = u1;
            *reinterpret_cast<uint2*>(
                &Ko[(((size_t)(bb * 12 + hh)) * 1024 + s) * 64 + d]) = uv;
        } else {
            const int c2 = nbase - 1536;
            const int hh = c2 >> 6, d = c2 & 63;
#pragma unroll
            for (int r = 0; r < 4; ++r)
                Vto[(((size_t)(bb * 12 + hh)) * 64 + d + r) * 1024 + s] = f2bf(v4[r]);
        }
    }
}

// ---------------------------------------------------------------------------
// gemm3p: 128x128 tile, BK=32, FOUR LDS buffers (64KB), depth-3 prefetch.
// Per K-tile: {vmcnt(8) [tile t landed; t+1,t+2 in flight] | barrier |
// 8 asm ds_reads buf t&3 | stage(t+3 -> buf (t+3)&3) |
// lgkmcnt(3)->4 MFMA | lgkmcnt(2)->4 | lgkmcnt(1)->4 | lgkmcnt(0)->4}.
// ONE barrier per tile; counted waits throughout (drain only at t=NT-1).
// WAR: stage at t targets buf (t-1)&3, whose reads all completed before
// barrier(t) (each wave's reads finish before its MFMAs, before barrier).
// LDS placement: logical (row R, 16B-unit cu) at physical unit
// R*4 + (cu ^ ((R>>1)&3))  (2-way, conflict-free -- measured 0).
// ---------------------------------------------------------------------------
template <int MODE>
__global__ __launch_bounds__(256) void gemm3p(
    const short* __restrict__ A, const short* __restrict__ Wt,
    const float* __restrict__ bias, const float* __restrict__ resid,
    float* __restrict__ outf, short* __restrict__ outh,
    short* __restrict__ Qo, short* __restrict__ Ko, short* __restrict__ Vto,
    int M, int N, int K) {
    __shared__ __attribute__((aligned(128))) short Al[4][4096];
    __shared__ __attribute__((aligned(128))) short Bl[4][4096];
    const int tid = threadIdx.x;
    const int lane = tid & 63;
    const int w = tid >> 6;
    const int wm = w >> 1, wn = w & 1;
    const int m0 = blockIdx.x * 128, n0 = blockIdx.y * 128;

    f32x4 acc[4][4] = {};

    // staging: thread tid fills physical unit tid (linear dest); logical
    // source unit cu = (tid&3) ^ ((tid>>3)&3).
    const int srow = tid >> 2;
    const int scol = (((tid & 3) ^ ((tid >> 3) & 3)) * 8);
    const short* Abase = A + (size_t)(m0 + srow) * K + scol;
    const short* Bbase = Wt + (size_t)(n0 + srow) * K + scol;
    const size_t K64 = (size_t)K * 64;
    short* const AlF = &Al[0][0];
    short* const BlF = &Bl[0][0];

    auto stageT = [&](int boS, int k0s) {
        gload_lds16(Abase + k0s,       AlF + boS + w * 512);
        gload_lds16(Abase + K64 + k0s, AlF + boS + 2048 + w * 512);
        gload_lds16(Bbase + k0s,       BlF + boS + w * 512);
        gload_lds16(Bbase + K64 + k0s, BlF + boS + 2048 + w * 512);
    };

    // fragment read: logical (R = l15 + 16*mi, cu = g) at physical byte
    // R*64 + (g ^ ((R>>1)&3))*16; 16*mi preserves the swizzle bits.
    const int l15 = lane & 15, g = lane >> 4;
    const int lcolswz = (g ^ ((l15 >> 1) & 3)) << 4;
    const int aoff = wm * 4096 + l15 * 64 + lcolswz;
    const int boff = wn * 4096 + l15 * 64 + lcolswz;
    const lds_cp AlB = (lds_cp)AlF;
    const lds_cp BlB = (lds_cp)BlF;

    const int NT = K >> 5;  // 24 or 96 here (>= 4)

    // prologue: tiles 0,1,2 -> bufs 0,1,2 (12 loads outstanding)
    stageT(0, 0);
    stageT(4096, 32);
    stageT(8192, 64);

    for (int t = 0; t < NT; ++t) {
        if (t == NT - 1) { WAITV0; } else { WAITV8; }  // tile t landed
        SCHEDB;
        __builtin_amdgcn_s_barrier();

        const int bo = (t & 3) * 8192;  // byte offset of buf t&3
        const lds_cp Ab = AlB + (bo + aoff);
        const lds_cp Bb = BlB + (bo + boff);
        bf16x8 av0, av1, av2, av3, bv0, bv1, bv2, bv3;
        DSR(av0, Ab, 0);
        DSR(av1, Ab, 1024);
        DSR(av2, Ab, 2048);
        DSR(av3, Ab, 3072);
        DSR(bv0, Bb, 0);
        DSR(bv1, Bb, 1024);
        DSR(bv2, Bb, 2048);
        DSR(bv3, Bb, 3072);

        if (t + 3 < NT) stageT(((t + 3) & 3) * 4096, (t + 3) << 5);

        __builtin_amdgcn_s_setprio(1);
        WAITLG3;  // av0-3, bv0 landed (DS retires in order)
        SCHEDB;
        acc[0][0] = MFMA16(bv0, av0, acc[0][0]);
        acc[1][0] = MFMA16(bv0, av1, acc[1][0]);
        acc[2][0] = MFMA16(bv0, av2, acc[2][0]);
        acc[3][0] = MFMA16(bv0, av3, acc[3][0]);
        WAITLG2;  // bv1 landed
        SCHEDB;
        acc[0][1] = MFMA16(bv1, av0, acc[0][1]);
        acc[1][1] = MFMA16(bv1, av1, acc[1][1]);
        acc[2][1] = MFMA16(bv1, av2, acc[2][1]);
        acc[3][1] = MFMA16(bv1, av3, acc[3][1]);
        WAITLG1;  // bv2 landed
        SCHEDB;
        acc[0][2] = MFMA16(bv2, av0, acc[0][2]);
        acc[1][2] = MFMA16(bv2, av1, acc[1][2]);
        acc[2][2] = MFMA16(bv2, av2, acc[2][2]);
        acc[3][2] = MFMA16(bv2, av3, acc[3][2]);
        WAITLG;   // bv3 landed
        SCHEDB;
        acc[0][3] = MFMA16(bv3, av0, acc[0][3]);
        acc[1][3] = MFMA16(bv3, av1, acc[1][3]);
        acc[2][3] = MFMA16(bv3, av2, acc[2][3]);
        acc[3][3] = MFMA16(bv3, av3, acc[3][3]);
        __builtin_amdgcn_s_setprio(0);
    }

    // Epilogue: swapped D layout -> thread owns C[mrow][nbase..nbase+3].
#pragma unroll
    for (int ni = 0; ni < 4; ++ni) {
        const int nbase = n0 + wn * 64 + ni * 16 + g * 4;
        const float4 b4 = *reinterpret_cast<const float4*>(&bias[nbase]);
#pragma unroll
        for (int mi = 0; mi < 4; ++mi) {
            const int mrow = m0 + wm * 64 + mi * 16 + l15;
            float v4[4] = {acc[mi][ni][0] + b4.x, acc[mi][ni][1] + b4.y,
                           acc[mi][ni][2] + b4.z, acc[mi][ni][3] + b4.w};
            epi_store4<MODE>(v4, mrow, nbase, N, resid, outf, outh, Qo, Ko, Vto);
        }
    }
}

// ---------------------------------------------------------------------------
// Flash attention, swapped-operand softmax (unchanged from round 8).
// ---------------------------------------------------------------------------
__global__ __launch_bounds__(256) void attn_k(
    const short* __restrict__ Q, const short* __restrict__ Kg,
    const short* __restrict__ Vtg, short* __restrict__ out) {
    __shared__ __attribute__((aligned(128))) short Kl[2][64 * 64];
    __shared__ __attribute__((aligned(128))) short Vl[2][64 * 64];
    __shared__ __attribute__((aligned(128))) short Pl[4][16 * 64];
    const int tid = threadIdx.x, lane = tid & 63, w = tid >> 6;
    const int swz = (blockIdx.x & 7) * 192 + (blockIdx.x >> 3);
    const int qt = swz & 15, bh = swz >> 4;
    const int b = bh / 12, h = bh % 12;
    const int q0 = qt * 64 + w * 16;
    const int l15 = lane & 15, g = lane >> 4;

    bf16x8 aq[2];
    const short* Qb = Q + ((size_t)bh * 1024 + q0) * 64;
#pragma unroll
    for (int kk = 0; kk < 2; ++kk)
        aq[kk] = *(const bf16x8*)&Qb[(size_t)l15 * 64 + kk * 32 + g * 8];

    float m_run = -1e30f, l_run = 0.f;
    f32x4 o[4] = {};

    const short* Kb = Kg + (size_t)bh * 1024 * 64;
    const short* Vb = Vtg + (size_t)bh * 64 * 1024;

    const int srr = tid >> 3;
    const int spp = (tid & 7) * 8;
    const int ssc = spp ^ ((srr & 7) << 3);
    auto stage = [&](int buf, int kv0) {
        gload_lds16(Kb + (size_t)(kv0 + srr) * 64 + ssc,        &Kl[buf][w * 512]);
        gload_lds16(Kb + (size_t)(kv0 + 32 + srr) * 64 + ssc,   &Kl[buf][2048 + w * 512]);
        gload_lds16(Vb + (size_t)srr * 1024 + kv0 + ssc,        &Vl[buf][w * 512]);
        gload_lds16(Vb + (size_t)(srr + 32) * 1024 + kv0 + ssc, &Vl[buf][2048 + w * 512]);
    };

    stage(0, 0);
    __syncthreads();

    int buf = 0;
    for (int t = 0; t < 16; ++t) {
        const lds_cp KB = (lds_cp)&Kl[buf][0];
        const lds_cp VB = (lds_cp)&Vl[buf][0];

        bf16x8 kb[4][2];
#pragma unroll
        for (int nk = 0; nk < 4; ++nk) {
            const int R = nk * 16 + l15;
            const int c0 = (g * 8) ^ ((R & 7) << 3);
            const lds_cp a0 = KB + R * 128 + c0 * 2;
            const lds_cp a1 = KB + R * 128 + (c0 ^ 32) * 2;
            DSR(kb[nk][0], a0, 0);
            DSR(kb[nk][1], a1, 0);
        }

        if (t < 15) stage(buf ^ 1, (t + 1) * 64);

        WAITLG;
        SCHEDB;

        f32x4 sc4[4];
#pragma unroll
        for (int nk = 0; nk < 4; ++nk) {
            f32x4 z = {};
            z = MFMA16(kb[nk][0], aq[0], z);
            z = MFMA16(kb[nk][1], aq[1], z);
            sc4[nk] = z;
        }

        float ml = sc4[0][0];
#pragma unroll
        for (int nk = 0; nk < 4; ++nk)
#pragma unroll
            for (int r = 0; r < 4; ++r) ml = fmaxf(ml, sc4[nk][r]);
        ml = fmaxf(ml, __shfl_xor(ml, 16));
        ml = fmaxf(ml, __shfl_xor(ml, 32));
        const float mn = fmaxf(m_run, ml);
        const float alpha = __expf(m_run - mn);
        m_run = mn;
        float padd[4][4];
        float rsum = 0.f;
#pragma unroll
        for (int nk = 0; nk < 4; ++nk)
#pragma unroll
            for (int r = 0; r < 4; ++r) {
                padd[nk][r] = __expf(sc4[nk][r] - mn);
                rsum += padd[nk][r];
            }
        rsum += __shfl_xor(rsum, 16);
        rsum += __shfl_xor(rsum, 32);
        l_run = l_run * alpha + rsum;
#pragma unroll
        for (int dn = 0; dn < 4; ++dn) o[dn] *= alpha;

#pragma unroll
        for (int nk = 0; nk < 4; ++nk) {
            unsigned u0, u1;
            CVTPK(u0, padd[nk][0], padd[nk][1]);
            CVTPK(u1, padd[nk][2], padd[nk][3]);
            const int cc = (nk * 16 + g * 4) ^ ((l15 & 7) << 3);
            uint2 uv; uv.x = u0; uv.y = u1;
            *reinterpret_cast<uint2*>(&Pl[w][l15 * 64 + cc]) = uv;
        }
        bf16x8 pa[2];
#pragma unroll
        for (int kk = 0; kk < 2; ++kk)
            pa[kk] = *(const bf16x8*)&Pl[w][l15 * 64 + ((kk * 32 + g * 8) ^ ((l15 & 7) << 3))];

        bf16x8 vb[4][2];
#pragma unroll
        for (int dn = 0; dn < 4; ++dn) {
            const int R = dn * 16 + l15;
            const int c0 = (g * 8) ^ ((R & 7) << 3);
            const lds_cp a0 = VB + R * 128 + c0 * 2;
            const lds_cp a1 = VB + R * 128 + (c0 ^ 32) * 2;
            DSR(vb[dn][0], a0, 0);
            DSR(vb[dn][1], a1, 0);
        }
        WAITLG;
        SCHEDB;

#pragma unroll
        for (int dn = 0; dn < 4; ++dn) {
            o[dn] = MFMA16(vb[dn][0], pa[0], o[dn]);
            o[dn] = MFMA16(vb[dn][1], pa[1], o[dn]);
        }

        __syncthreads();
        buf ^= 1;
    }

    const float rl = __builtin_amdgcn_rcpf(l_run);
    short* orow = out + ((size_t)(b * 1024) + q0 + l15) * 768 + h * 64;
#pragma unroll
    for (int dn = 0; dn < 4; ++dn) {
        unsigned u0, u1;
        const float v0 = o[dn][0] * rl, v1 = o[dn][1] * rl;
        const float v2 = o[dn][2] * rl, v3 = o[dn][3] * rl;
        CVTPK(u0, v0, v1);
        CVTPK(u1, v2, v3);
        uint2 uv; uv.x = u0; uv.y = u1;
        *reinterpret_cast<uint2*>(&orow[dn * 16 + g * 4]) = uv;
    }
}

// ---------------------------------------------------------------------------
// Launch
// ---------------------------------------------------------------------------
extern "C" void kernel_launch(void* const* d_in, const int* in_sizes, int n_in,
                              void* d_out, int out_size, void* d_ws, size_t ws_size,
                              hipStream_t stream) {
    const float* x      = (const float*)d_in[0];
    const float* ln1_g  = (const float*)d_in[1];
    const float* ln1_b  = (const float*)d_in[2];
    const float* qkv_w  = (const float*)d_in[3];
    const float* qkv_b  = (const float*)d_in[4];
    const float* proj_w = (const float*)d_in[5];
    const float* proj_b = (const float*)d_in[6];
    const float* ln2_g  = (const float*)d_in[7];
    const float* ln2_b  = (const float*)d_in[8];
    const float* fc1_w  = (const float*)d_in[9];
    const float* fc1_b  = (const float*)d_in[10];
    const float* fc2_w  = (const float*)d_in[11];
    const float* fc2_b  = (const float*)d_in[12];
    float* outp = (float*)d_out;

    char* ws = (char*)d_ws;
    size_t off = 0;
    auto alloc = [&](size_t bytes) {
        char* p = ws + off;
        off = (off + bytes + 255) & ~(size_t)255;
        return p;
    };
    short* wt_qkv  = (short*)alloc(2304ull * 768 * 2);
    short* wt_proj = (short*)alloc(768ull * 768 * 2);
    short* wt_fc1  = (short*)alloc(3072ull * 768 * 2);
    short* wt_fc2  = (short*)alloc(768ull * 3072 * 2);
    short* hbuf    = (short*)alloc(8192ull * 768 * 2);
    short* Qb      = (short*)alloc(8192ull * 768 * 2);   // [B,NH,S,HD]
    short* Kbuf    = (short*)alloc(8192ull * 768 * 2);   // [B,NH,S,HD]
    short* Vtb     = (short*)alloc(8192ull * 768 * 2);   // [B,NH,HD,S]
    short* attnb   = (short*)alloc(8192ull * 768 * 2);   // [B,S,H]
    float* x2      = (float*)alloc(8192ull * 768 * 4);   // fp32 residual stream
    short* mfc     = Qb;  // alias: fc1 output [8192,3072] over dead Q/K/Vt/attn
    (void)ws_size; (void)in_sizes; (void)n_in; (void)out_size;

    // weight prep (merged: 1728+576+2304+2304 = 6912 blocks)
    transpose_all<<<6912, 256, 0, stream>>>(qkv_w, proj_w, fc1_w, fc2_w,
                                            wt_qkv, wt_proj, wt_fc1, wt_fc2);

    // attention sublayer
    ln_k<<<8192, 192, 0, stream>>>(x, ln1_g, ln1_b, hbuf);
    gemm3p<MODE_QKV><<<dim3(64, 18), 256, 0, stream>>>(
        hbuf, wt_qkv, qkv_b, nullptr, nullptr, nullptr, Qb, Kbuf, Vtb, 8192, 2304, 768);
    attn_k<<<1536, 256, 0, stream>>>(Qb, Kbuf, Vtb, attnb);
    gemm3p<MODE_F32RES><<<dim3(64, 6), 256, 0, stream>>>(
        attnb, wt_proj, proj_b, x, x2, nullptr, nullptr, nullptr, nullptr, 8192, 768, 768);

    // MLP sublayer
    ln_k<<<8192, 192, 0, stream>>>(x2, ln2_g, ln2_b, hbuf);
    gemm3p<MODE_GELU><<<dim3(64, 24), 256, 0, stream>>>(
        hbuf, wt_fc1, fc1_b, nullptr, nullptr, mfc, nullptr, nullptr, nullptr, 8192, 3072, 768);
    gemm3p<MODE_F32RES><<<dim3(64, 6), 256, 0, stream>>>(
        mfc, wt_fc2, fc2_b, x2, outp, nullptr, nullptr, nullptr, nullptr, 8192, 768, 3072);
}